// Round 1
// baseline (897.720 us; speedup 1.0000x reference)
//
#include <hip/hip_runtime.h>
#include <hip/hip_bf16.h>
#include <math.h>

// Problem constants
#define GRIDN 14
#define L 197          // 14*14+1
#define H 12
#define DK 64
#define D 768
#define B 32
#define BL (B*L)       // 6304
#define TOPK 32

#define QKV_ELEMS ((size_t)B*H*L*DK)   // 4,841,472

// ---------------------------------------------------------------------------
// Tiled fp32 GEMM core: C = A(MxK) @ W(KxN) + bias, 64x64 tile, 256 threads,
// 4x4 microtile per thread. As stored transposed (As[kk][m]) so the inner
// loop does two ds_read_b128 per kk.
// mode 0: write to (B,H,L,DK) layout (row=b*197+l, col=h*64+d)
// mode 1: plain row-major MxN
// ---------------------------------------------------------------------------
#define BM 64
#define BN 64
#define BK 32

__device__ __forceinline__ void gemm_body(
    const float* __restrict__ A, const float* __restrict__ W,
    const float* __restrict__ bias, float* __restrict__ C,
    int M, int N, int K, int mode)
{
    __shared__ float As[BK][BM + 4];
    __shared__ float Bs[BK][BN + 4];

    const int tid = threadIdx.x;
    const int tx = tid & 15;         // 0..15  -> 4 cols each
    const int ty = tid >> 4;         // 0..15  -> 4 rows each
    const int m0 = blockIdx.x * BM;
    const int n0 = blockIdx.y * BN;

    float acc[4][4] = {};

    for (int k0 = 0; k0 < K; k0 += BK) {
        // Load A tile (64 rows x 32 k), 512 float4 total, 2 per thread.
        #pragma unroll
        for (int u = 0; u < 2; ++u) {
            int idx = tid + u * 256;
            int r = idx >> 3;            // 0..63
            int c4 = idx & 7;            // 0..7 (float4 within 32 k)
            int gm = m0 + r;
            float4 v = make_float4(0.f, 0.f, 0.f, 0.f);
            if (gm < M) v = *(const float4*)&A[(size_t)gm * K + k0 + c4 * 4];
            As[c4 * 4 + 0][r] = v.x;
            As[c4 * 4 + 1][r] = v.y;
            As[c4 * 4 + 2][r] = v.z;
            As[c4 * 4 + 3][r] = v.w;
        }
        // Load B tile (32 k x 64 n), coalesced float4.
        #pragma unroll
        for (int u = 0; u < 2; ++u) {
            int idx = tid + u * 256;
            int kk = idx >> 4;           // 0..31
            int n4 = idx & 15;           // 0..15
            float4 v = *(const float4*)&W[(size_t)(k0 + kk) * N + n0 + n4 * 4];
            *(float4*)&Bs[kk][n4 * 4] = v;
        }
        __syncthreads();

        #pragma unroll
        for (int kk = 0; kk < BK; ++kk) {
            float4 a4 = *(const float4*)&As[kk][ty * 4];
            float4 b4 = *(const float4*)&Bs[kk][tx * 4];
            float a[4] = {a4.x, a4.y, a4.z, a4.w};
            float b[4] = {b4.x, b4.y, b4.z, b4.w};
            #pragma unroll
            for (int ii = 0; ii < 4; ++ii)
                #pragma unroll
                for (int jj = 0; jj < 4; ++jj)
                    acc[ii][jj] += a[ii] * b[jj];
        }
        __syncthreads();
    }

    #pragma unroll
    for (int ii = 0; ii < 4; ++ii) {
        int m = m0 + ty * 4 + ii;
        if (m >= M) break;
        #pragma unroll
        for (int jj = 0; jj < 4; ++jj) {
            int n = n0 + tx * 4 + jj;
            float v = acc[ii][jj] + bias[n];
            if (mode == 0) {
                int bb = m / L, ll = m % L;
                int hh = n >> 6, dd = n & 63;
                C[((((size_t)bb * H + hh) * L + ll) << 6) + dd] = v;
            } else {
                C[(size_t)m * N + n] = v;
            }
        }
    }
}

// QKV: blockIdx.z selects which projection; writes (B,H,L,DK) layout.
__global__ __launch_bounds__(256)
void gemm_qkv(const float* __restrict__ x,
              const float* __restrict__ Wq, const float* __restrict__ bq,
              const float* __restrict__ Wk, const float* __restrict__ bk,
              const float* __restrict__ Wv, const float* __restrict__ bv,
              float* __restrict__ Qb, float* __restrict__ Kb, float* __restrict__ Vb)
{
    const float* W; const float* bias; float* C;
    if (blockIdx.z == 0)      { W = Wq; bias = bq; C = Qb; }
    else if (blockIdx.z == 1) { W = Wk; bias = bk; C = Kb; }
    else                      { W = Wv; bias = bv; C = Vb; }
    gemm_body(x, W, bias, C, BL, D, D, 0);
}

// Output projection: out = cons @ W_o + b_o, plain row-major.
__global__ __launch_bounds__(256)
void gemm_o(const float* __restrict__ cons, const float* __restrict__ Wo,
            const float* __restrict__ bo, float* __restrict__ out)
{
    gemm_body(cons, Wo, bo, out, BL, D, D, 1);
}

// ---------------------------------------------------------------------------
// Attention kernel: one 64-thread block (one wave) per (b,h,i) row.
//  - builds valid-j list (row 0: all 197; patch rows: cls + Chebyshev<=2,
//    <=26 entries, so TOP_K=32 only filters row 0)
//  - lane-per-dim dist^2 with butterfly reduce (fp32 to keep the
//    weights>1e-6 mask boundary exact vs the fp32 reference)
//  - exact top-32 selection for row 0 (lowest-index tie-break = lax.top_k)
//  - softmax, dense 197-wide weight+mask row write, fused consensus = w @ V
// ---------------------------------------------------------------------------
__global__ __launch_bounds__(64)
void attn(const float* __restrict__ Q, const float* __restrict__ Km,
          const float* __restrict__ V, const float* __restrict__ logsig,
          float* __restrict__ wout, float* __restrict__ mout,
          float* __restrict__ cons)
{
    const int row = blockIdx.x;          // (b*H + h)*L + i
    const int i = row % L;
    const int bh = row / L;
    const int b = bh / H, h = bh % H;
    const int lane = threadIdx.x;

    __shared__ int   jl[L];
    __shared__ float sc[L];
    __shared__ float dense[L];
    __shared__ unsigned char sel[L];
    __shared__ int nvalid_s;

    // ---- valid list ----
    if (i == 0) {
        for (int t = lane; t < L; t += 64) jl[t] = t;
        if (lane == 0) nvalid_s = L;
    } else {
        if (lane == 0) {
            int n = 0;
            jl[n++] = 0;
            int r = (i - 1) / GRIDN, c = (i - 1) % GRIDN;
            int r0 = r - 2 < 0 ? 0 : r - 2;
            int r1 = r + 2 > GRIDN - 1 ? GRIDN - 1 : r + 2;
            int c0 = c - 2 < 0 ? 0 : c - 2;
            int c1 = c + 2 > GRIDN - 1 ? GRIDN - 1 : c + 2;
            for (int rr = r0; rr <= r1; ++rr)
                for (int cc = c0; cc <= c1; ++cc)
                    jl[n++] = 1 + rr * GRIDN + cc;
            nvalid_s = n;
        }
    }
    __syncthreads();
    const int n = nvalid_s;

    // ---- scores ----
    const float sigsq = expf(2.0f * logsig[0]);
    const float coef = -0.5f / sigsq;
    const float* Kbase = Km + (size_t)bh * L * DK;
    const float q = Q[((size_t)bh * L + i) * DK + lane];

    for (int t = 0; t < n; ++t) {
        float kv = Kbase[jl[t] * DK + lane];
        float dv = q - kv;
        float s = dv * dv;
        #pragma unroll
        for (int off = 32; off; off >>= 1) s += __shfl_xor(s, off);
        if (lane == 0) sc[t] = coef * s;
    }
    __syncthreads();

    // ---- selection (top-32 only matters for row 0) ----
    for (int t = lane; t < L; t += 64) sel[t] = (i != 0) ? 1 : 0;
    __syncthreads();
    if (i == 0) {
        for (int it = 0; it < TOPK; ++it) {
            float bv = -INFINITY; int bi = 1 << 30;
            for (int t = lane; t < L; t += 64) {
                if (!sel[t]) {
                    float v = sc[t];
                    if (v > bv || (v == bv && t < bi)) { bv = v; bi = t; }
                }
            }
            #pragma unroll
            for (int off = 32; off; off >>= 1) {
                float ov = __shfl_xor(bv, off);
                int   oi = __shfl_xor(bi, off);
                if (ov > bv || (ov == bv && oi < bi)) { bv = ov; bi = oi; }
            }
            if (lane == 0) sel[bi] = 1;
            __syncthreads();
        }
    }

    // ---- softmax over active entries ----
    float mx = -INFINITY;
    for (int t = lane; t < n; t += 64) if (sel[t]) mx = fmaxf(mx, sc[t]);
    #pragma unroll
    for (int off = 32; off; off >>= 1) mx = fmaxf(mx, __shfl_xor(mx, off));

    float z = 0.f;
    for (int t = lane; t < n; t += 64) {
        float w = sel[t] ? expf(sc[t] - mx) : 0.f;
        sc[t] = w;                    // numerator
        z += w;
    }
    #pragma unroll
    for (int off = 32; off; off >>= 1) z += __shfl_xor(z, off);

    // ---- dense row (weights + mask) ----
    for (int t = lane; t < L; t += 64) dense[t] = 0.f;
    __syncthreads();
    for (int t = lane; t < n; t += 64)
        if (sel[t]) dense[jl[t]] = sc[t] / z;   // division matches softmax
    __syncthreads();

    const size_t wb = (size_t)row * L;
    for (int t = lane; t < L; t += 64) {
        float w = dense[t];
        wout[wb + t] = w;
        mout[wb + t] = (w > 1e-6f) ? 1.0f : 0.0f;
    }

    // ---- consensus: cons[b, i, h*64+lane] = sum_j w[j] * V[j, lane] ----
    const float* Vbase = V + (size_t)bh * L * DK;
    float acc = 0.f;
    for (int t = 0; t < n; ++t) {
        int j = jl[t];
        float w = dense[j];
        if (w != 0.f) acc += w * Vbase[j * DK + lane];
    }
    cons[((size_t)b * L + i) * D + h * DK + lane] = acc;
}

// ---------------------------------------------------------------------------
extern "C" void kernel_launch(void* const* d_in, const int* in_sizes, int n_in,
                              void* d_out, int out_size, void* d_ws, size_t ws_size,
                              hipStream_t stream)
{
    const float* x   = (const float*)d_in[0];
    const float* Wq  = (const float*)d_in[1];
    const float* bq  = (const float*)d_in[2];
    const float* Wk  = (const float*)d_in[3];
    const float* bk  = (const float*)d_in[4];
    const float* Wv  = (const float*)d_in[5];
    const float* bv  = (const float*)d_in[6];
    const float* Wo  = (const float*)d_in[7];
    const float* bo  = (const float*)d_in[8];
    const float* lsg = (const float*)d_in[9];

    float* out  = (float*)d_out;                       // B*L*D
    float* wout = out + QKV_ELEMS;                     // B*H*L*L
    float* mout = wout + (size_t)B * H * L * L;        // B*H*L*L

    float* Qb    = (float*)d_ws;
    float* Kb    = Qb + QKV_ELEMS;
    float* Vb    = Kb + QKV_ELEMS;
    float* consb = Vb + QKV_ELEMS;

    dim3 gqkv((BL + BM - 1) / BM, D / BN, 3);
    gemm_qkv<<<gqkv, 256, 0, stream>>>(x, Wq, bq, Wk, bk, Wv, bv, Qb, Kb, Vb);

    attn<<<B * H * L, 64, 0, stream>>>(Qb, Kb, Vb, lsg, wout, mout, consb);

    dim3 go((BL + BM - 1) / BM, D / BN, 1);
    gemm_o<<<go, 256, 0, stream>>>(consb, Wo, bo, out);
}

// Round 2
// 675.781 us; speedup vs baseline: 1.3284x; 1.3284x over previous
//
#include <hip/hip_runtime.h>
#include <hip/hip_bf16.h>
#include <math.h>

#define GRIDN 14
#define L 197
#define H 12
#define DK 64
#define D 768
#define B 32
#define BL (B*L)          // 6304
#define TOPK 32
#define NBH (B*H)         // 384
#define NROW (NBH*L)      // 75648
#define QKV_ELEMS ((size_t)NROW*DK)

// ---------------------------------------------------------------------------
// fp32 GEMM: 128x128 tile, 256 threads, 8x8 microtile (split 4+4 fragments).
// mode 0: write (B,H,L,DK) layout; mode 1: row-major.
// ---------------------------------------------------------------------------
#define BM 128
#define BN 128
#define BK 16

__device__ __forceinline__ void gemm_body(
    const float* __restrict__ A, const float* __restrict__ W,
    const float* __restrict__ bias, float* __restrict__ C,
    int M, int mode)
{
    __shared__ float As[BK][BM + 4];   // transposed A tile: As[kk][m]
    __shared__ float Bs[BK][BN + 4];

    const int tid = threadIdx.x;
    const int tx = tid & 15;
    const int ty = tid >> 4;
    const int m0 = blockIdx.x * BM;
    const int n0 = blockIdx.y * BN;

    float acc[8][8] = {};

    for (int k0 = 0; k0 < D; k0 += BK) {
        // A tile: 128 rows x 16 k  (512 float4, 2/thread)
        #pragma unroll
        for (int u = 0; u < 2; ++u) {
            int idx = tid + u * 256;
            int r = idx >> 2, c4 = idx & 3;
            int gm = m0 + r;
            float4 v = make_float4(0.f, 0.f, 0.f, 0.f);
            if (gm < M) v = *(const float4*)&A[(size_t)gm * D + k0 + c4 * 4];
            As[c4 * 4 + 0][r] = v.x;
            As[c4 * 4 + 1][r] = v.y;
            As[c4 * 4 + 2][r] = v.z;
            As[c4 * 4 + 3][r] = v.w;
        }
        // B tile: 16 k x 128 n
        #pragma unroll
        for (int u = 0; u < 2; ++u) {
            int idx = tid + u * 256;
            int kk = idx >> 5, n4 = idx & 31;
            *(float4*)&Bs[kk][n4 * 4] =
                *(const float4*)&W[(size_t)(k0 + kk) * D + n0 + n4 * 4];
        }
        __syncthreads();

        #pragma unroll
        for (int kk = 0; kk < BK; ++kk) {
            float4 a0 = *(const float4*)&As[kk][ty * 4];
            float4 a1 = *(const float4*)&As[kk][64 + ty * 4];
            float4 b0 = *(const float4*)&Bs[kk][tx * 4];
            float4 b1 = *(const float4*)&Bs[kk][64 + tx * 4];
            float a[8] = {a0.x, a0.y, a0.z, a0.w, a1.x, a1.y, a1.z, a1.w};
            float b[8] = {b0.x, b0.y, b0.z, b0.w, b1.x, b1.y, b1.z, b1.w};
            #pragma unroll
            for (int ii = 0; ii < 8; ++ii)
                #pragma unroll
                for (int jj = 0; jj < 8; ++jj)
                    acc[ii][jj] += a[ii] * b[jj];
        }
        __syncthreads();
    }

    #pragma unroll
    for (int ih = 0; ih < 2; ++ih) {
        #pragma unroll
        for (int ii = 0; ii < 4; ++ii) {
            int m = m0 + ih * 64 + ty * 4 + ii;
            if (m >= M) continue;
            #pragma unroll
            for (int jh = 0; jh < 2; ++jh) {
                int n = n0 + jh * 64 + tx * 4;
                float4 bv = *(const float4*)&bias[n];
                float4 rr;
                rr.x = acc[ih * 4 + ii][jh * 4 + 0] + bv.x;
                rr.y = acc[ih * 4 + ii][jh * 4 + 1] + bv.y;
                rr.z = acc[ih * 4 + ii][jh * 4 + 2] + bv.z;
                rr.w = acc[ih * 4 + ii][jh * 4 + 3] + bv.w;
                if (mode == 0) {
                    int bb = m / L, ll = m % L;
                    int hh = n >> 6, dd = n & 63;
                    *(float4*)&C[((((size_t)bb * H + hh) * L + ll) << 6) + dd] = rr;
                } else {
                    *(float4*)&C[(size_t)m * D + n] = rr;
                }
            }
        }
    }
}

__global__ __launch_bounds__(256)
void gemm_qkv(const float* __restrict__ x,
              const float* __restrict__ Wq, const float* __restrict__ bq,
              const float* __restrict__ Wk, const float* __restrict__ bk,
              const float* __restrict__ Wv, const float* __restrict__ bv,
              float* __restrict__ Qb, float* __restrict__ Kb, float* __restrict__ Vb)
{
    const float* W; const float* bias; float* C;
    if (blockIdx.z == 0)      { W = Wq; bias = bq; C = Qb; }
    else if (blockIdx.z == 1) { W = Wk; bias = bk; C = Kb; }
    else                      { W = Wv; bias = bv; C = Vb; }
    gemm_body(x, W, bias, C, BL, 0);
}

__global__ __launch_bounds__(256)
void gemm_o(const float* __restrict__ cons, const float* __restrict__ Wo,
            const float* __restrict__ bo, float* __restrict__ out)
{
    gemm_body(cons, Wo, bo, out, BL, 1);
}

// ---------------------------------------------------------------------------
// attn_scores: one block per (b,h). K staged in LDS (stride 65). One wave per
// row; 2 lanes per candidate j; exact top-32 for cls row. Writes dense
// weights+mask and compact (w, j) lists.
// ---------------------------------------------------------------------------
__global__ __launch_bounds__(512)
void attn_scores(const float* __restrict__ Q, const float* __restrict__ Kg,
                 const float* __restrict__ logsig,
                 float* __restrict__ wout, float* __restrict__ mout,
                 float* __restrict__ wC, unsigned char* __restrict__ jC)
{
    __shared__ float Ks[L * 65];
    __shared__ float qbuf[8][64];
    __shared__ float ws[8][32];
    __shared__ float clsbuf[L];

    const int bh = blockIdx.x;
    const int tid = threadIdx.x, wave = tid >> 6, lane = tid & 63;

    const float* Kp = Kg + (size_t)bh * L * DK;
    for (int idx = tid; idx < L * 16; idx += 512) {
        int r = idx >> 4, c4 = idx & 15;
        float4 v = *(const float4*)&Kp[r * 64 + c4 * 4];
        float* dst = &Ks[r * 65 + c4 * 4];
        dst[0] = v.x; dst[1] = v.y; dst[2] = v.z; dst[3] = v.w;
    }
    __syncthreads();

    const float coef = -0.5f * expf(-2.0f * logsig[0]);
    const int starts[9] = {0, 18, 44, 70, 96, 122, 148, 172, 197};

    for (int i = starts[wave]; i < starts[wave + 1]; ++i) {
        const int rowid = bh * L + i;
        const size_t wb = (size_t)rowid * L;

        qbuf[wave][lane] = Q[(size_t)rowid * 64 + lane];   // in-wave LDS (DS in-order)

        int r = 0, c = 0, r0 = 0, c0 = 0, r1 = 0, c1 = 0, Wd = 0, n = L;
        if (i > 0) {
            r = (i - 1) / GRIDN; c = (i - 1) % GRIDN;
            r0 = r - 2 < 0 ? 0 : r - 2;  r1 = r + 2 > 13 ? 13 : r + 2;
            c0 = c - 2 < 0 ? 0 : c - 2;  c1 = c + 2 > 13 ? 13 : c + 2;
            Wd = c1 - c0 + 1;
            n = (r1 - r0 + 1) * Wd + 1;
        }

        if (i == 0) {
            // ---- cls row: 197 candidates, 7 passes ----
            for (int p = 0; p < 7; ++p) {
                int t = (p << 5) + (lane >> 1);
                bool valid = t < L;
                float s = 0.f;
                if (valid) {
                    const float* kp = &Ks[t * 65 + ((lane & 1) << 5)];
                    const float* qp = &qbuf[wave][(lane & 1) << 5];
                    #pragma unroll
                    for (int d2 = 0; d2 < 32; ++d2) {
                        float dv = qp[d2] - kp[d2];
                        s += dv * dv;
                    }
                }
                s += __shfl_xor(s, 1);
                if (valid && !(lane & 1)) clsbuf[t] = coef * s;
            }
            // exact top-32 (lowest-index tie-break = lax.top_k membership)
            float orig[4], cur[4]; int selb = 0;
            #pragma unroll
            for (int k = 0; k < 4; ++k) {
                int t = lane + (k << 6);
                float v = (t < L) ? clsbuf[t] : -INFINITY;
                orig[k] = v; cur[k] = v;
            }
            float gmax = -INFINITY;
            for (int it = 0; it < TOPK; ++it) {
                float bv = cur[0]; int bt = lane;
                #pragma unroll
                for (int k = 1; k < 4; ++k)
                    if (cur[k] > bv) { bv = cur[k]; bt = lane + (k << 6); }
                #pragma unroll
                for (int off = 32; off; off >>= 1) {
                    float ov = __shfl_xor(bv, off);
                    int   ot = __shfl_xor(bt, off);
                    if (ov > bv || (ov == bv && ot < bt)) { bv = ov; bt = ot; }
                }
                if (it == 0) gmax = bv;
                if ((bt & 63) == lane) { cur[bt >> 6] = -INFINITY; selb |= 1 << (bt >> 6); }
            }
            float zl = 0.f; float wk[4];
            #pragma unroll
            for (int k = 0; k < 4; ++k) {
                wk[k] = ((selb >> k) & 1) ? expf(orig[k] - gmax) : 0.f;
                zl += wk[k];
            }
            #pragma unroll
            for (int off = 32; off; off >>= 1) zl += __shfl_xor(zl, off);

            #pragma unroll
            for (int k = 0; k < 4; ++k) {
                int p = lane + (k << 6);
                if (p < L) {
                    float wv = wk[k] / zl;          // exact 0 for unselected
                    wout[wb + p] = wv;
                    mout[wb + p] = (wv > 1e-6f) ? 1.f : 0.f;
                }
            }
            // compact list via ballot (order within list is irrelevant for the sum)
            int slot = 0;
            #pragma unroll
            for (int k = 0; k < 4; ++k) {
                bool sel = (selb >> k) & 1;
                unsigned long long mk = __ballot(sel);
                if (sel) {
                    int tt = slot + (int)__popcll(mk & ((1ull << lane) - 1ull));
                    wC[(size_t)rowid * 32 + tt] = wk[k] / zl;
                    jC[(size_t)rowid * 32 + tt] = (unsigned char)(lane + (k << 6));
                }
                slot += (int)__popcll(mk);
            }
        } else {
            // ---- patch row: n <= 26, single pass, top-k is a no-op ----
            int t = lane >> 1;
            bool valid = t < n;
            float s = 0.f; int j = 0;
            if (valid) {
                if (t > 0) {
                    int tm = t - 1;
                    j = 1 + (r0 + tm / Wd) * GRIDN + (c0 + tm % Wd);
                }
                const float* kp = &Ks[j * 65 + ((lane & 1) << 5)];
                const float* qp = &qbuf[wave][(lane & 1) << 5];
                #pragma unroll
                for (int d2 = 0; d2 < 32; ++d2) {
                    float dv = qp[d2] - kp[d2];
                    s += dv * dv;
                }
            }
            s += __shfl_xor(s, 1);
            float sc = valid ? coef * s : -INFINITY;

            float mx = sc;
            #pragma unroll
            for (int off = 32; off; off >>= 1) mx = fmaxf(mx, __shfl_xor(mx, off));
            float e = valid ? expf(sc - mx) : 0.f;
            float es = (lane & 1) ? 0.f : e;
            #pragma unroll
            for (int off = 32; off; off >>= 1) es += __shfl_xor(es, off);
            float wv = e / es;

            if (!(lane & 1)) {
                float wcv = valid ? wv : 0.f;
                ws[wave][t] = wcv;
                wC[(size_t)rowid * 32 + t] = wcv;
                jC[(size_t)rowid * 32 + t] = (unsigned char)(valid ? j : 0);
            }
            // dense weight/mask row
            #pragma unroll
            for (int k = 0; k < 4; ++k) {
                int p = lane + (k << 6);
                if (p < L) {
                    float wd = 0.f;
                    if (p == 0) wd = ws[wave][0];
                    else {
                        int pr = (p - 1) / GRIDN, pc = (p - 1) % GRIDN;
                        if (pr >= r0 && pr <= r1 && pc >= c0 && pc <= c1)
                            wd = ws[wave][1 + (pr - r0) * Wd + (pc - c0)];
                    }
                    wout[wb + p] = wd;
                    mout[wb + p] = (wd > 1e-6f) ? 1.f : 0.f;
                }
            }
        }
    }
}

// ---------------------------------------------------------------------------
// attn_cons: one block per (b,h); V staged in LDS; consensus from compact
// (w, j) lists. cons written in (B, L, D) layout for the O-projection.
// ---------------------------------------------------------------------------
__global__ __launch_bounds__(512)
void attn_cons(const float* __restrict__ Vg, const float* __restrict__ wC,
               const unsigned char* __restrict__ jC, float* __restrict__ cons)
{
    __shared__ float Vs[L * 64];
    __shared__ float wsb[8][32];
    __shared__ int   jsb[8][32];

    const int bh = blockIdx.x;
    const int b = bh / H, h = bh % H;
    const int tid = threadIdx.x, wave = tid >> 6, lane = tid & 63;

    const float* Vp = Vg + (size_t)bh * L * 64;
    for (int idx = tid; idx < L * 16; idx += 512)
        *(float4*)&Vs[idx * 4] = *(const float4*)&Vp[idx * 4];
    __syncthreads();

    const int starts[9] = {0, 25, 50, 75, 100, 125, 150, 174, 197};
    for (int i = starts[wave]; i < starts[wave + 1]; ++i) {
        const int rowid = bh * L + i;
        if (lane < 32) {
            wsb[wave][lane] = wC[(size_t)rowid * 32 + lane];
            jsb[wave][lane] = (int)jC[(size_t)rowid * 32 + lane];
        }
        float acc = 0.f;
        #pragma unroll
        for (int t4 = 0; t4 < 8; ++t4) {
            float4 w4 = *(const float4*)&wsb[wave][t4 * 4];
            int4   j4 = *(const int4*)&jsb[wave][t4 * 4];
            acc += w4.x * Vs[j4.x * 64 + lane];
            acc += w4.y * Vs[j4.y * 64 + lane];
            acc += w4.z * Vs[j4.z * 64 + lane];
            acc += w4.w * Vs[j4.w * 64 + lane];
        }
        cons[((size_t)b * L + i) * D + h * 64 + lane] = acc;
    }
}

// ---------------------------------------------------------------------------
extern "C" void kernel_launch(void* const* d_in, const int* in_sizes, int n_in,
                              void* d_out, int out_size, void* d_ws, size_t ws_size,
                              hipStream_t stream)
{
    const float* x   = (const float*)d_in[0];
    const float* Wq  = (const float*)d_in[1];
    const float* bq  = (const float*)d_in[2];
    const float* Wk  = (const float*)d_in[3];
    const float* bk  = (const float*)d_in[4];
    const float* Wv  = (const float*)d_in[5];
    const float* bv  = (const float*)d_in[6];
    const float* Wo  = (const float*)d_in[7];
    const float* bo  = (const float*)d_in[8];
    const float* lsg = (const float*)d_in[9];

    float* out  = (float*)d_out;                       // B*L*D
    float* wout = out + QKV_ELEMS;                     // B*H*L*L
    float* mout = wout + (size_t)B * H * L * L;        // B*H*L*L

    float* Qb    = (float*)d_ws;
    float* Kb    = Qb + QKV_ELEMS;
    float* Vb    = Kb + QKV_ELEMS;
    float* consb = Vb + QKV_ELEMS;
    float* wCb   = consb + QKV_ELEMS;
    unsigned char* jCb = (unsigned char*)(wCb + (size_t)NROW * 32);

    dim3 gq((BL + BM - 1) / BM, D / BN, 3);
    gemm_qkv<<<gq, 256, 0, stream>>>(x, Wq, bq, Wk, bk, Wv, bv, Qb, Kb, Vb);

    attn_scores<<<NBH, 512, 0, stream>>>(Qb, Kb, lsg, wout, mout, wCb, jCb);
    attn_cons<<<NBH, 512, 0, stream>>>(Vb, wCb, jCb, consb);

    dim3 go((BL + BM - 1) / BM, D / BN, 1);
    gemm_o<<<go, 256, 0, stream>>>(consb, Wo, bo, out);
}

// Round 3
// 571.123 us; speedup vs baseline: 1.5719x; 1.1832x over previous
//
#include <hip/hip_runtime.h>
#include <hip/hip_bf16.h>
#include <math.h>

#define GRIDN 14
#define L 197
#define H 12
#define DK 64
#define D 768
#define B 32
#define BL (B*L)          // 6304
#define TOPK 32
#define NBH (B*H)         // 384
#define NROW (NBH*L)      // 75648
#define QKV_ELEMS ((size_t)NROW*DK)

typedef __attribute__((ext_vector_type(8))) short short8;   // 8 bf16
typedef __attribute__((ext_vector_type(4))) float floatx4;

// ---------------------------------------------------------------------------
// cast/prep: x -> bf16 row-major; Wv, Wo -> bf16 TRANSPOSED [n][k]
// ---------------------------------------------------------------------------
__global__ __launch_bounds__(256)
void cast_prep(const float* __restrict__ x, const float* __restrict__ Wv,
               const float* __restrict__ Wo,
               __hip_bfloat16* __restrict__ xb,
               __hip_bfloat16* __restrict__ WvT,
               __hip_bfloat16* __restrict__ WoT)
{
    int tid = blockIdx.x * blockDim.x + threadIdx.x;
    int stride = gridDim.x * blockDim.x;
    for (int i = tid; i < BL * D; i += stride)
        xb[i] = __float2bfloat16(x[i]);
    for (int i = tid; i < D * D; i += stride) {
        int n = i / D, k = i % D;
        WvT[i] = __float2bfloat16(Wv[(size_t)k * D + n]);
        WoT[i] = __float2bfloat16(Wo[(size_t)k * D + n]);
    }
}

// ---------------------------------------------------------------------------
// fp32 GEMM for Q,K: 128x128 tile, 256 threads, 8x8 microtile, register
// prefetch of the next global tile across the FMA block.
// Writes (B,H,L,DK) layout.
// ---------------------------------------------------------------------------
#define BM 128
#define BN 128
#define BK 16

__global__ __launch_bounds__(256)
void gemm_qk(const float* __restrict__ x,
             const float* __restrict__ Wq, const float* __restrict__ bq,
             const float* __restrict__ Wk, const float* __restrict__ bk,
             float* __restrict__ Qb, float* __restrict__ Kb)
{
    const float* Wm; const float* bias; float* C;
    if (blockIdx.z == 0) { Wm = Wq; bias = bq; C = Qb; }
    else                 { Wm = Wk; bias = bk; C = Kb; }

    __shared__ float As[BK][BM + 4];
    __shared__ float Bs[BK][BN + 4];

    const int tid = threadIdx.x;
    const int tx = tid & 15, ty = tid >> 4;
    const int m0 = blockIdx.x * BM, n0 = blockIdx.y * BN;

    float acc[8][8] = {};

    int a_r[2], a_c[2], b_k[2], b_n[2];
    float4 pa[2], pb[2];
    #pragma unroll
    for (int u = 0; u < 2; ++u) {
        int idx = tid + u * 256;
        a_r[u] = idx >> 2; a_c[u] = idx & 3;
        b_k[u] = idx >> 5; b_n[u] = idx & 31;
    }
    #pragma unroll
    for (int u = 0; u < 2; ++u) {
        int gm = m0 + a_r[u]; if (gm >= BL) gm = BL - 1;
        pa[u] = *(const float4*)&x[(size_t)gm * D + a_c[u] * 4];
        pb[u] = *(const float4*)&Wm[(size_t)b_k[u] * D + n0 + b_n[u] * 4];
    }

    for (int k0 = 0; k0 < D; k0 += BK) {
        #pragma unroll
        for (int u = 0; u < 2; ++u) {
            As[a_c[u] * 4 + 0][a_r[u]] = pa[u].x;
            As[a_c[u] * 4 + 1][a_r[u]] = pa[u].y;
            As[a_c[u] * 4 + 2][a_r[u]] = pa[u].z;
            As[a_c[u] * 4 + 3][a_r[u]] = pa[u].w;
            *(float4*)&Bs[b_k[u]][b_n[u] * 4] = pb[u];
        }
        __syncthreads();

        if (k0 + BK < D) {
            #pragma unroll
            for (int u = 0; u < 2; ++u) {
                int gm = m0 + a_r[u]; if (gm >= BL) gm = BL - 1;
                pa[u] = *(const float4*)&x[(size_t)gm * D + k0 + BK + a_c[u] * 4];
                pb[u] = *(const float4*)&Wm[(size_t)(k0 + BK + b_k[u]) * D + n0 + b_n[u] * 4];
            }
        }

        #pragma unroll
        for (int kk = 0; kk < BK; ++kk) {
            float4 a0 = *(const float4*)&As[kk][ty * 4];
            float4 a1 = *(const float4*)&As[kk][64 + ty * 4];
            float4 b0 = *(const float4*)&Bs[kk][tx * 4];
            float4 b1 = *(const float4*)&Bs[kk][64 + tx * 4];
            float a[8] = {a0.x, a0.y, a0.z, a0.w, a1.x, a1.y, a1.z, a1.w};
            float b[8] = {b0.x, b0.y, b0.z, b0.w, b1.x, b1.y, b1.z, b1.w};
            #pragma unroll
            for (int ii = 0; ii < 8; ++ii)
                #pragma unroll
                for (int jj = 0; jj < 8; ++jj)
                    acc[ii][jj] += a[ii] * b[jj];
        }
        __syncthreads();
    }

    #pragma unroll
    for (int ih = 0; ih < 2; ++ih) {
        #pragma unroll
        for (int ii = 0; ii < 4; ++ii) {
            int m = m0 + ih * 64 + ty * 4 + ii;
            if (m >= BL) continue;
            #pragma unroll
            for (int jh = 0; jh < 2; ++jh) {
                int n = n0 + jh * 64 + tx * 4;
                float4 bv = *(const float4*)&bias[n];
                float4 rr;
                rr.x = acc[ih * 4 + ii][jh * 4 + 0] + bv.x;
                rr.y = acc[ih * 4 + ii][jh * 4 + 1] + bv.y;
                rr.z = acc[ih * 4 + ii][jh * 4 + 2] + bv.z;
                rr.w = acc[ih * 4 + ii][jh * 4 + 3] + bv.w;
                int bb = m / L, ll = m % L;
                int hh = n >> 6, dd = n & 63;
                *(float4*)&C[((((size_t)bb * H + hh) * L + ll) << 6) + dd] = rr;
            }
        }
    }
}

// ---------------------------------------------------------------------------
// bf16 MFMA GEMM: A[M][768] bf16 row-major, Bt[768][768] bf16 n-major,
// 128x128 tile, 4 waves in 2x2 quadrants, 16x16x32 MFMA, global_load_lds.
// MODE 0: C fp32 (B,H,L,DK); MODE 1: C fp32 row-major.
// ---------------------------------------------------------------------------
#define TBK 32

__device__ __forceinline__ void load_lds16(void* lds, const void* g) {
    __builtin_amdgcn_global_load_lds(
        (const __attribute__((address_space(1))) unsigned int*)g,
        (__attribute__((address_space(3))) unsigned int*)lds, 16, 0, 0);
}

template<int MODE>
__global__ __launch_bounds__(256)
void gemm_bf16(const __hip_bfloat16* __restrict__ A,
               const __hip_bfloat16* __restrict__ Bt,
               const float* __restrict__ bias,
               float* __restrict__ C)
{
    __shared__ __attribute__((aligned(16))) __hip_bfloat16 As[128][TBK];
    __shared__ __attribute__((aligned(16))) __hip_bfloat16 Bts[128][TBK];

    const int tid = threadIdx.x;
    const int wave = tid >> 6, lane = tid & 63;
    const int quad = lane >> 4, l16 = lane & 15;
    const int m0 = blockIdx.x * 128, n0 = blockIdx.y * 128;
    const int wm = (wave & 1) * 64, wn = (wave >> 1) * 64;

    floatx4 acc[4][4] = {};

    // per-thread staging chunk coords (16B chunks; idx = tid + u*256)
    int s_r[2], s_c[2];
    #pragma unroll
    for (int u = 0; u < 2; ++u) {
        int idx = tid + u * 256;
        s_r[u] = idx >> 2; s_c[u] = idx & 3;
    }

    for (int k0 = 0; k0 < D; k0 += TBK) {
        #pragma unroll
        for (int u = 0; u < 2; ++u) {
            int gm = m0 + s_r[u]; if (gm >= BL) gm = BL - 1;
            char* abase = (char*)&As[0][0] + ((wave * 64 + u * 256) * 16);
            load_lds16(abase, A + (size_t)gm * D + k0 + s_c[u] * 8);
            char* bbase = (char*)&Bts[0][0] + ((wave * 64 + u * 256) * 16);
            load_lds16(bbase, Bt + (size_t)(n0 + s_r[u]) * D + k0 + s_c[u] * 8);
        }
        __syncthreads();

        short8 af[4], bf[4];
        #pragma unroll
        for (int a = 0; a < 4; ++a)
            af[a] = *(const short8*)&As[wm + a * 16 + l16][quad * 8];
        #pragma unroll
        for (int b2 = 0; b2 < 4; ++b2)
            bf[b2] = *(const short8*)&Bts[wn + b2 * 16 + l16][quad * 8];
        #pragma unroll
        for (int a = 0; a < 4; ++a)
            #pragma unroll
            for (int b2 = 0; b2 < 4; ++b2)
                acc[a][b2] = __builtin_amdgcn_mfma_f32_16x16x32_bf16(
                    af[a], bf[b2], acc[a][b2], 0, 0, 0);
        __syncthreads();
    }

    #pragma unroll
    for (int b2 = 0; b2 < 4; ++b2) {
        int n = n0 + wn + b2 * 16 + l16;
        float bv = bias[n];
        #pragma unroll
        for (int a = 0; a < 4; ++a) {
            #pragma unroll
            for (int r = 0; r < 4; ++r) {
                int m = m0 + wm + a * 16 + quad * 4 + r;
                if (m < BL) {
                    float v = acc[a][b2][r] + bv;
                    if (MODE == 0) {
                        int bb = m / L, ll = m % L;
                        int hh = n >> 6, dd = n & 63;
                        C[((((size_t)bb * H + hh) * L + ll) << 6) + dd] = v;
                    } else {
                        C[(size_t)m * D + n] = v;
                    }
                }
            }
        }
    }
}

// ---------------------------------------------------------------------------
// attn_scores: grid (NBH, 2); K staged in LDS; one wave per row.
// ---------------------------------------------------------------------------
__global__ __launch_bounds__(512)
void attn_scores(const float* __restrict__ Q, const float* __restrict__ Kg,
                 const float* __restrict__ logsig,
                 float* __restrict__ wout, float* __restrict__ mout,
                 float* __restrict__ wC, unsigned char* __restrict__ jC)
{
    __shared__ float Ks[L * 65];
    __shared__ float qbuf[8][64];
    __shared__ float ws[8][32];
    __shared__ float clsbuf[L];

    const int bh = blockIdx.x;
    const int yb = blockIdx.y;
    const int tid = threadIdx.x, wave = tid >> 6, lane = tid & 63;

    const float* Kp = Kg + (size_t)bh * L * DK;
    for (int idx = tid; idx < L * 16; idx += 512) {
        int r = idx >> 4, c4 = idx & 15;
        float4 v = *(const float4*)&Kp[r * 64 + c4 * 4];
        float* dst = &Ks[r * 65 + c4 * 4];
        dst[0] = v.x; dst[1] = v.y; dst[2] = v.z; dst[3] = v.w;
    }
    __syncthreads();

    const float coef = -0.5f * expf(-2.0f * logsig[0]);
    const int starts0[9] = {0, 9, 22, 35, 48, 61, 74, 87, 99};
    const int starts1[9] = {99, 112, 124, 136, 148, 161, 173, 185, 197};
    const int i_begin = yb ? starts1[wave] : starts0[wave];
    const int i_end   = yb ? starts1[wave + 1] : starts0[wave + 1];

    for (int i = i_begin; i < i_end; ++i) {
        const int rowid = bh * L + i;
        const size_t wb = (size_t)rowid * L;

        qbuf[wave][lane] = Q[(size_t)rowid * 64 + lane];

        int r = 0, c = 0, r0 = 0, c0 = 0, r1 = 0, c1 = 0, Wd = 0, n = L;
        if (i > 0) {
            r = (i - 1) / GRIDN; c = (i - 1) % GRIDN;
            r0 = r - 2 < 0 ? 0 : r - 2;  r1 = r + 2 > 13 ? 13 : r + 2;
            c0 = c - 2 < 0 ? 0 : c - 2;  c1 = c + 2 > 13 ? 13 : c + 2;
            Wd = c1 - c0 + 1;
            n = (r1 - r0 + 1) * Wd + 1;
        }

        if (i == 0) {
            for (int p = 0; p < 7; ++p) {
                int t = (p << 5) + (lane >> 1);
                bool valid = t < L;
                float s = 0.f;
                if (valid) {
                    const float* kp = &Ks[t * 65 + ((lane & 1) << 5)];
                    const float* qp = &qbuf[wave][(lane & 1) << 5];
                    #pragma unroll
                    for (int d2 = 0; d2 < 32; ++d2) {
                        float dv = qp[d2] - kp[d2];
                        s += dv * dv;
                    }
                }
                s += __shfl_xor(s, 1);
                if (valid && !(lane & 1)) clsbuf[t] = coef * s;
            }
            float orig[4], cur[4]; int selb = 0;
            #pragma unroll
            for (int k = 0; k < 4; ++k) {
                int t = lane + (k << 6);
                float v = (t < L) ? clsbuf[t] : -INFINITY;
                orig[k] = v; cur[k] = v;
            }
            float gmax = -INFINITY;
            for (int it = 0; it < TOPK; ++it) {
                float bv = cur[0]; int bt = lane;
                #pragma unroll
                for (int k = 1; k < 4; ++k)
                    if (cur[k] > bv) { bv = cur[k]; bt = lane + (k << 6); }
                #pragma unroll
                for (int off = 32; off; off >>= 1) {
                    float ov = __shfl_xor(bv, off);
                    int   ot = __shfl_xor(bt, off);
                    if (ov > bv || (ov == bv && ot < bt)) { bv = ov; bt = ot; }
                }
                if (it == 0) gmax = bv;
                if ((bt & 63) == lane) { cur[bt >> 6] = -INFINITY; selb |= 1 << (bt >> 6); }
            }
            float zl = 0.f; float wk[4];
            #pragma unroll
            for (int k = 0; k < 4; ++k) {
                wk[k] = ((selb >> k) & 1) ? expf(orig[k] - gmax) : 0.f;
                zl += wk[k];
            }
            #pragma unroll
            for (int off = 32; off; off >>= 1) zl += __shfl_xor(zl, off);

            #pragma unroll
            for (int k = 0; k < 4; ++k) {
                int p = lane + (k << 6);
                if (p < L) {
                    float wv = wk[k] / zl;
                    wout[wb + p] = wv;
                    mout[wb + p] = (wv > 1e-6f) ? 1.f : 0.f;
                }
            }
            int slot = 0;
            #pragma unroll
            for (int k = 0; k < 4; ++k) {
                bool sel = (selb >> k) & 1;
                unsigned long long mk = __ballot(sel);
                if (sel) {
                    int tt = slot + (int)__popcll(mk & ((1ull << lane) - 1ull));
                    wC[(size_t)rowid * 32 + tt] = wk[k] / zl;
                    jC[(size_t)rowid * 32 + tt] = (unsigned char)(lane + (k << 6));
                }
                slot += (int)__popcll(mk);
            }
        } else {
            int t = lane >> 1;
            bool valid = t < n;
            float s = 0.f; int j = 0;
            if (valid) {
                if (t > 0) {
                    int tm = t - 1;
                    j = 1 + (r0 + tm / Wd) * GRIDN + (c0 + tm % Wd);
                }
                const float* kp = &Ks[j * 65 + ((lane & 1) << 5)];
                const float* qp = &qbuf[wave][(lane & 1) << 5];
                #pragma unroll
                for (int d2 = 0; d2 < 32; ++d2) {
                    float dv = qp[d2] - kp[d2];
                    s += dv * dv;
                }
            }
            s += __shfl_xor(s, 1);
            float sc = valid ? coef * s : -INFINITY;

            float mx = sc;
            #pragma unroll
            for (int off = 32; off; off >>= 1) mx = fmaxf(mx, __shfl_xor(mx, off));
            float e = valid ? expf(sc - mx) : 0.f;
            float es = (lane & 1) ? 0.f : e;
            #pragma unroll
            for (int off = 32; off; off >>= 1) es += __shfl_xor(es, off);
            float wv = e / es;

            if (!(lane & 1)) {
                float wcv = valid ? wv : 0.f;
                ws[wave][t] = wcv;
                wC[(size_t)rowid * 32 + t] = wcv;
                jC[(size_t)rowid * 32 + t] = (unsigned char)(valid ? j : 0);
            }
            #pragma unroll
            for (int k = 0; k < 4; ++k) {
                int p = lane + (k << 6);
                if (p < L) {
                    float wd = 0.f;
                    if (p == 0) wd = ws[wave][0];
                    else {
                        int pr = (p - 1) / GRIDN, pc = (p - 1) % GRIDN;
                        if (pr >= r0 && pr <= r1 && pc >= c0 && pc <= c1)
                            wd = ws[wave][1 + (pr - r0) * Wd + (pc - c0)];
                    }
                    wout[wb + p] = wd;
                    mout[wb + p] = (wd > 1e-6f) ? 1.f : 0.f;
                }
            }
        }
    }
}

// ---------------------------------------------------------------------------
// attn_cons: grid (NBH, 2); V staged in LDS; writes consensus as bf16
// in (B, L, D) row-major for the O-projection.
// ---------------------------------------------------------------------------
__global__ __launch_bounds__(512)
void attn_cons(const float* __restrict__ Vg, const float* __restrict__ wC,
               const unsigned char* __restrict__ jC,
               __hip_bfloat16* __restrict__ cons)
{
    __shared__ float Vs[L * 64];
    __shared__ float wsb[8][32];
    __shared__ int   jsb[8][32];

    const int bh = blockIdx.x;
    const int yb = blockIdx.y;
    const int b = bh / H, h = bh % H;
    const int tid = threadIdx.x, wave = tid >> 6, lane = tid & 63;

    const float* Vp = Vg + (size_t)bh * L * 64;
    for (int idx = tid; idx < L * 16; idx += 512)
        *(float4*)&Vs[idx * 4] = *(const float4*)&Vp[idx * 4];
    __syncthreads();

    const int starts0[9] = {0, 13, 26, 38, 50, 62, 74, 87, 99};
    const int starts1[9] = {99, 112, 124, 136, 148, 161, 173, 185, 197};
    const int i_begin = yb ? starts1[wave] : starts0[wave];
    const int i_end   = yb ? starts1[wave + 1] : starts0[wave + 1];

    for (int i = i_begin; i < i_end; ++i) {
        const int rowid = bh * L + i;
        if (lane < 32) {
            wsb[wave][lane] = wC[(size_t)rowid * 32 + lane];
            jsb[wave][lane] = (int)jC[(size_t)rowid * 32 + lane];
        }
        float acc = 0.f;
        #pragma unroll
        for (int t4 = 0; t4 < 8; ++t4) {
            float4 w4 = *(const float4*)&wsb[wave][t4 * 4];
            int4   j4 = *(const int4*)&jsb[wave][t4 * 4];
            acc += w4.x * Vs[j4.x * 64 + lane];
            acc += w4.y * Vs[j4.y * 64 + lane];
            acc += w4.z * Vs[j4.z * 64 + lane];
            acc += w4.w * Vs[j4.w * 64 + lane];
        }
        cons[((size_t)b * L + i) * D + h * 64 + lane] = __float2bfloat16(acc);
    }
}

// ---------------------------------------------------------------------------
extern "C" void kernel_launch(void* const* d_in, const int* in_sizes, int n_in,
                              void* d_out, int out_size, void* d_ws, size_t ws_size,
                              hipStream_t stream)
{
    const float* x   = (const float*)d_in[0];
    const float* Wq  = (const float*)d_in[1];
    const float* bq  = (const float*)d_in[2];
    const float* Wk  = (const float*)d_in[3];
    const float* bk  = (const float*)d_in[4];
    const float* Wv  = (const float*)d_in[5];
    const float* bv  = (const float*)d_in[6];
    const float* Wo  = (const float*)d_in[7];
    const float* bo  = (const float*)d_in[8];
    const float* lsg = (const float*)d_in[9];

    float* out  = (float*)d_out;                       // B*L*D
    float* wout = out + QKV_ELEMS;                     // B*H*L*L
    float* mout = wout + (size_t)B * H * L * L;        // B*H*L*L

    float* Qb  = (float*)d_ws;
    float* Kb  = Qb + QKV_ELEMS;
    float* Vb  = Kb + QKV_ELEMS;
    float* wCb = Vb + QKV_ELEMS;
    unsigned char* jCb = (unsigned char*)(wCb + (size_t)NROW * 32);
    __hip_bfloat16* xb    = (__hip_bfloat16*)(jCb + (size_t)NROW * 32);
    __hip_bfloat16* consb = xb;   // alias: xb dead after gemm_bf16<0>
    __hip_bfloat16* WvT = xb + (size_t)BL * D;
    __hip_bfloat16* WoT = WvT + (size_t)D * D;

    cast_prep<<<512, 256, 0, stream>>>(x, Wv, Wo, xb, WvT, WoT);

    dim3 gqk((BL + BM - 1) / BM, D / BN, 2);
    gemm_qk<<<gqk, 256, 0, stream>>>(x, Wq, bq, Wk, bk, Qb, Kb);

    dim3 gmm((BL + 127) / 128, D / 128);
    gemm_bf16<0><<<gmm, 256, 0, stream>>>(xb, WvT, bv, Vb);

    dim3 ga(NBH, 2);
    attn_scores<<<ga, 512, 0, stream>>>(Qb, Kb, lsg, wout, mout, wCb, jCb);
    attn_cons<<<ga, 512, 0, stream>>>(Vb, wCb, jCb, consb);

    gemm_bf16<1><<<gmm, 256, 0, stream>>>(consb, WoT, bo, out);
}

// Round 4
// 405.371 us; speedup vs baseline: 2.2146x; 1.4089x over previous
//
#include <hip/hip_runtime.h>
#include <hip/hip_bf16.h>
#include <math.h>

#define GRIDN 14
#define L 197
#define H 12
#define DK 64
#define D 768
#define B 32
#define BL (B*L)          // 6304
#define TOPK 32
#define NBH (B*H)         // 384
#define NROW (NBH*L)      // 75648
#define QKV_ELEMS ((size_t)NROW*DK)

typedef __attribute__((ext_vector_type(8))) short short8;   // 8 bf16
typedef __attribute__((ext_vector_type(4))) float floatx4;

__device__ __forceinline__ void load_lds16(void* lds, const void* g) {
    __builtin_amdgcn_global_load_lds(
        (const __attribute__((address_space(1))) unsigned int*)g,
        (__attribute__((address_space(3))) unsigned int*)lds, 16, 0, 0);
}

// ---------------------------------------------------------------------------
// cast_x: x (fp32) -> x_hi, x_lo (bf16), row-major, vectorized.
// ---------------------------------------------------------------------------
__global__ __launch_bounds__(256)
void cast_x(const float* __restrict__ x,
            __hip_bfloat16* __restrict__ xh, __hip_bfloat16* __restrict__ xl)
{
    int i = blockIdx.x * 256 + threadIdx.x;
    if (i >= BL * D / 4) return;
    float4 v = ((const float4*)x)[i];
    union { __hip_bfloat16 b[4]; short4 s; } hh, ll;
    float f[4] = {v.x, v.y, v.z, v.w};
    #pragma unroll
    for (int j = 0; j < 4; ++j) {
        __hip_bfloat16 h = __float2bfloat16(f[j]);
        hh.b[j] = h;
        ll.b[j] = __float2bfloat16(f[j] - __bfloat162float(h));
    }
    ((short4*)xh)[i] = hh.s;
    ((short4*)xl)[i] = ll.s;
}

// ---------------------------------------------------------------------------
// transpose_w: LDS-tiled transpose+cast. z=0:Wq(hi+lo) z=1:Wk(hi+lo)
// z=2:Wv(hi) z=3:Wo(hi). Output [n][k] bf16.
// ---------------------------------------------------------------------------
__global__ __launch_bounds__(256)
void transpose_w(const float* __restrict__ Wq, const float* __restrict__ Wk,
                 const float* __restrict__ Wv, const float* __restrict__ Wo,
                 __hip_bfloat16* __restrict__ WqTh, __hip_bfloat16* __restrict__ WqTl,
                 __hip_bfloat16* __restrict__ WkTh, __hip_bfloat16* __restrict__ WkTl,
                 __hip_bfloat16* __restrict__ WvT,  __hip_bfloat16* __restrict__ WoT)
{
    __shared__ float tile[32][33];
    const int z = blockIdx.z;
    const float* src = (z == 0) ? Wq : (z == 1) ? Wk : (z == 2) ? Wv : Wo;
    __hip_bfloat16* dh = (z == 0) ? WqTh : (z == 1) ? WkTh : (z == 2) ? WvT : WoT;
    __hip_bfloat16* dl = (z == 0) ? WqTl : (z == 1) ? WkTl : nullptr;
    const int k0 = blockIdx.y * 32, n0 = blockIdx.x * 32;
    const int tx = threadIdx.x & 31, ty = threadIdx.x >> 5;

    for (int r = ty; r < 32; r += 8)
        tile[r][tx] = src[(size_t)(k0 + r) * D + n0 + tx];
    __syncthreads();
    for (int r = ty; r < 32; r += 8) {
        float v = tile[tx][r];                       // src[k0+tx][n0+r]
        __hip_bfloat16 h = __float2bfloat16(v);
        dh[(size_t)(n0 + r) * D + k0 + tx] = h;
        if (dl) dl[(size_t)(n0 + r) * D + k0 + tx] =
            __float2bfloat16(v - __bfloat162float(h));
    }
}

// ---------------------------------------------------------------------------
// gemm_qk_split: C = Ah*Bh + Ah*Bl + Al*Bh (split-bf16 ~ fp32 accuracy),
// 128x128 tile, 4 waves 2x2, 16x16x32 MFMA, global_load_lds staging.
// z selects Q / K. Writes fp32 (B,H,L,DK).
// ---------------------------------------------------------------------------
#define TBK 32

__global__ __launch_bounds__(256)
void gemm_qk_split(const __hip_bfloat16* __restrict__ Ah,
                   const __hip_bfloat16* __restrict__ Al,
                   const __hip_bfloat16* __restrict__ Bqh,
                   const __hip_bfloat16* __restrict__ Bql,
                   const __hip_bfloat16* __restrict__ Bkh,
                   const __hip_bfloat16* __restrict__ Bkl,
                   const float* __restrict__ bq, const float* __restrict__ bk,
                   float* __restrict__ Qb, float* __restrict__ Kb)
{
    const __hip_bfloat16 *Bth, *Btl; const float* bias; float* C;
    if (blockIdx.z == 0) { Bth = Bqh; Btl = Bql; bias = bq; C = Qb; }
    else                 { Bth = Bkh; Btl = Bkl; bias = bk; C = Kb; }

    __shared__ __attribute__((aligned(16))) __hip_bfloat16 Ash[128][TBK];
    __shared__ __attribute__((aligned(16))) __hip_bfloat16 Asl[128][TBK];
    __shared__ __attribute__((aligned(16))) __hip_bfloat16 Bsh[128][TBK];
    __shared__ __attribute__((aligned(16))) __hip_bfloat16 Bsl[128][TBK];

    const int tid = threadIdx.x;
    const int wave = tid >> 6, lane = tid & 63;
    const int quad = lane >> 4, l16 = lane & 15;
    const int m0 = blockIdx.x * 128, n0 = blockIdx.y * 128;
    const int wm = (wave & 1) * 64, wn = (wave >> 1) * 64;

    floatx4 acc[4][4] = {};

    int s_r[2], s_c[2];
    #pragma unroll
    for (int u = 0; u < 2; ++u) {
        int idx = tid + u * 256;
        s_r[u] = idx >> 2; s_c[u] = idx & 3;
    }

    for (int k0 = 0; k0 < D; k0 += TBK) {
        #pragma unroll
        for (int u = 0; u < 2; ++u) {
            int gm = m0 + s_r[u]; if (gm >= BL) gm = BL - 1;
            size_t aoff = (size_t)gm * D + k0 + s_c[u] * 8;
            size_t boff = (size_t)(n0 + s_r[u]) * D + k0 + s_c[u] * 8;
            int lds_off = (wave * 64 + u * 256) * 16;
            load_lds16((char*)&Ash[0][0] + lds_off, Ah + aoff);
            load_lds16((char*)&Asl[0][0] + lds_off, Al + aoff);
            load_lds16((char*)&Bsh[0][0] + lds_off, Bth + boff);
            load_lds16((char*)&Bsl[0][0] + lds_off, Btl + boff);
        }
        __syncthreads();

        short8 ah[4], al[4], bh[4], bl[4];
        #pragma unroll
        for (int a = 0; a < 4; ++a) {
            ah[a] = *(const short8*)&Ash[wm + a * 16 + l16][quad * 8];
            al[a] = *(const short8*)&Asl[wm + a * 16 + l16][quad * 8];
        }
        #pragma unroll
        for (int b2 = 0; b2 < 4; ++b2) {
            bh[b2] = *(const short8*)&Bsh[wn + b2 * 16 + l16][quad * 8];
            bl[b2] = *(const short8*)&Bsl[wn + b2 * 16 + l16][quad * 8];
        }
        #pragma unroll
        for (int a = 0; a < 4; ++a)
            #pragma unroll
            for (int b2 = 0; b2 < 4; ++b2) {
                acc[a][b2] = __builtin_amdgcn_mfma_f32_16x16x32_bf16(
                    al[a], bh[b2], acc[a][b2], 0, 0, 0);
                acc[a][b2] = __builtin_amdgcn_mfma_f32_16x16x32_bf16(
                    ah[a], bl[b2], acc[a][b2], 0, 0, 0);
                acc[a][b2] = __builtin_amdgcn_mfma_f32_16x16x32_bf16(
                    ah[a], bh[b2], acc[a][b2], 0, 0, 0);
            }
        __syncthreads();
    }

    #pragma unroll
    for (int b2 = 0; b2 < 4; ++b2) {
        int n = n0 + wn + b2 * 16 + l16;
        float bv = bias[n];
        #pragma unroll
        for (int a = 0; a < 4; ++a) {
            #pragma unroll
            for (int r = 0; r < 4; ++r) {
                int m = m0 + wm + a * 16 + quad * 4 + r;
                if (m < BL) {
                    float v = acc[a][b2][r] + bv;
                    int bb = m / L, ll = m % L;
                    int hh = n >> 6, dd = n & 63;
                    C[((((size_t)bb * H + hh) * L + ll) << 6) + dd] = v;
                }
            }
        }
    }
}

// ---------------------------------------------------------------------------
// bf16 MFMA GEMM (single-term) for V and O projections.
// MODE 0: C fp32 (B,H,L,DK); MODE 1: C fp32 row-major.
// ---------------------------------------------------------------------------
template<int MODE>
__global__ __launch_bounds__(256)
void gemm_bf16(const __hip_bfloat16* __restrict__ A,
               const __hip_bfloat16* __restrict__ Bt,
               const float* __restrict__ bias,
               float* __restrict__ C)
{
    __shared__ __attribute__((aligned(16))) __hip_bfloat16 As[128][TBK];
    __shared__ __attribute__((aligned(16))) __hip_bfloat16 Bts[128][TBK];

    const int tid = threadIdx.x;
    const int wave = tid >> 6, lane = tid & 63;
    const int quad = lane >> 4, l16 = lane & 15;
    const int m0 = blockIdx.x * 128, n0 = blockIdx.y * 128;
    const int wm = (wave & 1) * 64, wn = (wave >> 1) * 64;

    floatx4 acc[4][4] = {};

    int s_r[2], s_c[2];
    #pragma unroll
    for (int u = 0; u < 2; ++u) {
        int idx = tid + u * 256;
        s_r[u] = idx >> 2; s_c[u] = idx & 3;
    }

    for (int k0 = 0; k0 < D; k0 += TBK) {
        #pragma unroll
        for (int u = 0; u < 2; ++u) {
            int gm = m0 + s_r[u]; if (gm >= BL) gm = BL - 1;
            int lds_off = (wave * 64 + u * 256) * 16;
            load_lds16((char*)&As[0][0] + lds_off, A + (size_t)gm * D + k0 + s_c[u] * 8);
            load_lds16((char*)&Bts[0][0] + lds_off,
                       Bt + (size_t)(n0 + s_r[u]) * D + k0 + s_c[u] * 8);
        }
        __syncthreads();

        short8 af[4], bf[4];
        #pragma unroll
        for (int a = 0; a < 4; ++a)
            af[a] = *(const short8*)&As[wm + a * 16 + l16][quad * 8];
        #pragma unroll
        for (int b2 = 0; b2 < 4; ++b2)
            bf[b2] = *(const short8*)&Bts[wn + b2 * 16 + l16][quad * 8];
        #pragma unroll
        for (int a = 0; a < 4; ++a)
            #pragma unroll
            for (int b2 = 0; b2 < 4; ++b2)
                acc[a][b2] = __builtin_amdgcn_mfma_f32_16x16x32_bf16(
                    af[a], bf[b2], acc[a][b2], 0, 0, 0);
        __syncthreads();
    }

    #pragma unroll
    for (int b2 = 0; b2 < 4; ++b2) {
        int n = n0 + wn + b2 * 16 + l16;
        float bv = bias[n];
        #pragma unroll
        for (int a = 0; a < 4; ++a) {
            #pragma unroll
            for (int r = 0; r < 4; ++r) {
                int m = m0 + wm + a * 16 + quad * 4 + r;
                if (m < BL) {
                    float v = acc[a][b2][r] + bv;
                    if (MODE == 0) {
                        int bb = m / L, ll = m % L;
                        int hh = n >> 6, dd = n & 63;
                        C[((((size_t)bb * H + hh) * L + ll) << 6) + dd] = v;
                    } else {
                        C[(size_t)m * D + n] = v;
                    }
                }
            }
        }
    }
}

// ---------------------------------------------------------------------------
// attn_scores: grid (NBH, 2); K staged in LDS; one wave per row.
// ---------------------------------------------------------------------------
__global__ __launch_bounds__(512)
void attn_scores(const float* __restrict__ Q, const float* __restrict__ Kg,
                 const float* __restrict__ logsig,
                 float* __restrict__ wout, float* __restrict__ mout,
                 float* __restrict__ wC, unsigned char* __restrict__ jC)
{
    __shared__ float Ks[L * 65];
    __shared__ float qbuf[8][64];
    __shared__ float ws[8][32];
    __shared__ float clsbuf[L];

    const int bh = blockIdx.x;
    const int yb = blockIdx.y;
    const int tid = threadIdx.x, wave = tid >> 6, lane = tid & 63;

    const float* Kp = Kg + (size_t)bh * L * DK;
    for (int idx = tid; idx < L * 16; idx += 512) {
        int r = idx >> 4, c4 = idx & 15;
        float4 v = *(const float4*)&Kp[r * 64 + c4 * 4];
        float* dst = &Ks[r * 65 + c4 * 4];
        dst[0] = v.x; dst[1] = v.y; dst[2] = v.z; dst[3] = v.w;
    }
    __syncthreads();

    const float coef = -0.5f * expf(-2.0f * logsig[0]);
    const int starts0[9] = {0, 9, 22, 35, 48, 61, 74, 87, 99};
    const int starts1[9] = {99, 112, 124, 136, 148, 161, 173, 185, 197};
    const int i_begin = yb ? starts1[wave] : starts0[wave];
    const int i_end   = yb ? starts1[wave + 1] : starts0[wave + 1];

    for (int i = i_begin; i < i_end; ++i) {
        const int rowid = bh * L + i;
        const size_t wb = (size_t)rowid * L;

        qbuf[wave][lane] = Q[(size_t)rowid * 64 + lane];

        int r = 0, c = 0, r0 = 0, c0 = 0, r1 = 0, c1 = 0, Wd = 0, n = L;
        if (i > 0) {
            r = (i - 1) / GRIDN; c = (i - 1) % GRIDN;
            r0 = r - 2 < 0 ? 0 : r - 2;  r1 = r + 2 > 13 ? 13 : r + 2;
            c0 = c - 2 < 0 ? 0 : c - 2;  c1 = c + 2 > 13 ? 13 : c + 2;
            Wd = c1 - c0 + 1;
            n = (r1 - r0 + 1) * Wd + 1;
        }

        if (i == 0) {
            for (int p = 0; p < 7; ++p) {
                int t = (p << 5) + (lane >> 1);
                bool valid = t < L;
                float s = 0.f;
                if (valid) {
                    const float* kp = &Ks[t * 65 + ((lane & 1) << 5)];
                    const float* qp = &qbuf[wave][(lane & 1) << 5];
                    #pragma unroll
                    for (int d2 = 0; d2 < 32; ++d2) {
                        float dv = qp[d2] - kp[d2];
                        s += dv * dv;
                    }
                }
                s += __shfl_xor(s, 1);
                if (valid && !(lane & 1)) clsbuf[t] = coef * s;
            }
            float orig[4], cur[4]; int selb = 0;
            #pragma unroll
            for (int k = 0; k < 4; ++k) {
                int t = lane + (k << 6);
                float v = (t < L) ? clsbuf[t] : -INFINITY;
                orig[k] = v; cur[k] = v;
            }
            float gmax = -INFINITY;
            for (int it = 0; it < TOPK; ++it) {
                float bv = cur[0]; int bt = lane;
                #pragma unroll
                for (int k = 1; k < 4; ++k)
                    if (cur[k] > bv) { bv = cur[k]; bt = lane + (k << 6); }
                #pragma unroll
                for (int off = 32; off; off >>= 1) {
                    float ov = __shfl_xor(bv, off);
                    int   ot = __shfl_xor(bt, off);
                    if (ov > bv || (ov == bv && ot < bt)) { bv = ov; bt = ot; }
                }
                if (it == 0) gmax = bv;
                if ((bt & 63) == lane) { cur[bt >> 6] = -INFINITY; selb |= 1 << (bt >> 6); }
            }
            float zl = 0.f; float wk[4];
            #pragma unroll
            for (int k = 0; k < 4; ++k) {
                wk[k] = ((selb >> k) & 1) ? expf(orig[k] - gmax) : 0.f;
                zl += wk[k];
            }
            #pragma unroll
            for (int off = 32; off; off >>= 1) zl += __shfl_xor(zl, off);

            #pragma unroll
            for (int k = 0; k < 4; ++k) {
                int p = lane + (k << 6);
                if (p < L) {
                    float wv = wk[k] / zl;
                    wout[wb + p] = wv;
                    mout[wb + p] = (wv > 1e-6f) ? 1.f : 0.f;
                }
            }
            int slot = 0;
            #pragma unroll
            for (int k = 0; k < 4; ++k) {
                bool sel = (selb >> k) & 1;
                unsigned long long mk = __ballot(sel);
                if (sel) {
                    int tt = slot + (int)__popcll(mk & ((1ull << lane) - 1ull));
                    wC[(size_t)rowid * 32 + tt] = wk[k] / zl;
                    jC[(size_t)rowid * 32 + tt] = (unsigned char)(lane + (k << 6));
                }
                slot += (int)__popcll(mk);
            }
        } else {
            int t = lane >> 1;
            bool valid = t < n;
            float s = 0.f; int j = 0;
            if (valid) {
                if (t > 0) {
                    int tm = t - 1;
                    j = 1 + (r0 + tm / Wd) * GRIDN + (c0 + tm % Wd);
                }
                const float* kp = &Ks[j * 65 + ((lane & 1) << 5)];
                const float* qp = &qbuf[wave][(lane & 1) << 5];
                #pragma unroll
                for (int d2 = 0; d2 < 32; ++d2) {
                    float dv = qp[d2] - kp[d2];
                    s += dv * dv;
                }
            }
            s += __shfl_xor(s, 1);
            float sc = valid ? coef * s : -INFINITY;

            float mx = sc;
            #pragma unroll
            for (int off = 32; off; off >>= 1) mx = fmaxf(mx, __shfl_xor(mx, off));
            float e = valid ? expf(sc - mx) : 0.f;
            float es = (lane & 1) ? 0.f : e;
            #pragma unroll
            for (int off = 32; off; off >>= 1) es += __shfl_xor(es, off);
            float wv = e / es;

            if (!(lane & 1)) {
                float wcv = valid ? wv : 0.f;
                ws[wave][t] = wcv;
                wC[(size_t)rowid * 32 + t] = wcv;
                jC[(size_t)rowid * 32 + t] = (unsigned char)(valid ? j : 0);
            }
            #pragma unroll
            for (int k = 0; k < 4; ++k) {
                int p = lane + (k << 6);
                if (p < L) {
                    float wd = 0.f;
                    if (p == 0) wd = ws[wave][0];
                    else {
                        int pr = (p - 1) / GRIDN, pc = (p - 1) % GRIDN;
                        if (pr >= r0 && pr <= r1 && pc >= c0 && pc <= c1)
                            wd = ws[wave][1 + (pr - r0) * Wd + (pc - c0)];
                    }
                    wout[wb + p] = wd;
                    mout[wb + p] = (wd > 1e-6f) ? 1.f : 0.f;
                }
            }
        }
    }
}

// ---------------------------------------------------------------------------
// attn_cons: grid (NBH, 2); V staged in LDS; writes consensus as bf16
// in (B, L, D) row-major for the O-projection.
// ---------------------------------------------------------------------------
__global__ __launch_bounds__(512)
void attn_cons(const float* __restrict__ Vg, const float* __restrict__ wC,
               const unsigned char* __restrict__ jC,
               __hip_bfloat16* __restrict__ cons)
{
    __shared__ float Vs[L * 64];
    __shared__ float wsb[8][32];
    __shared__ int   jsb[8][32];

    const int bh = blockIdx.x;
    const int yb = blockIdx.y;
    const int b = bh / H, h = bh % H;
    const int tid = threadIdx.x, wave = tid >> 6, lane = tid & 63;

    const float* Vp = Vg + (size_t)bh * L * 64;
    for (int idx = tid; idx < L * 16; idx += 512)
        *(float4*)&Vs[idx * 4] = *(const float4*)&Vp[idx * 4];
    __syncthreads();

    const int starts0[9] = {0, 13, 26, 38, 50, 62, 74, 87, 99};
    const int starts1[9] = {99, 112, 124, 136, 148, 161, 173, 185, 197};
    const int i_begin = yb ? starts1[wave] : starts0[wave];
    const int i_end   = yb ? starts1[wave + 1] : starts0[wave + 1];

    for (int i = i_begin; i < i_end; ++i) {
        const int rowid = bh * L + i;
        if (lane < 32) {
            wsb[wave][lane] = wC[(size_t)rowid * 32 + lane];
            jsb[wave][lane] = (int)jC[(size_t)rowid * 32 + lane];
        }
        float acc = 0.f;
        #pragma unroll
        for (int t4 = 0; t4 < 8; ++t4) {
            float4 w4 = *(const float4*)&wsb[wave][t4 * 4];
            int4   j4 = *(const int4*)&jsb[wave][t4 * 4];
            acc += w4.x * Vs[j4.x * 64 + lane];
            acc += w4.y * Vs[j4.y * 64 + lane];
            acc += w4.z * Vs[j4.z * 64 + lane];
            acc += w4.w * Vs[j4.w * 64 + lane];
        }
        cons[((size_t)b * L + i) * D + h * 64 + lane] = __float2bfloat16(acc);
    }
}

// ---------------------------------------------------------------------------
extern "C" void kernel_launch(void* const* d_in, const int* in_sizes, int n_in,
                              void* d_out, int out_size, void* d_ws, size_t ws_size,
                              hipStream_t stream)
{
    const float* x   = (const float*)d_in[0];
    const float* Wq  = (const float*)d_in[1];
    const float* bq  = (const float*)d_in[2];
    const float* Wk  = (const float*)d_in[3];
    const float* bk  = (const float*)d_in[4];
    const float* Wv  = (const float*)d_in[5];
    const float* bv  = (const float*)d_in[6];
    const float* Wo  = (const float*)d_in[7];
    const float* bo  = (const float*)d_in[8];
    const float* lsg = (const float*)d_in[9];

    float* out  = (float*)d_out;                       // B*L*D
    float* wout = out + QKV_ELEMS;                     // B*H*L*L
    float* mout = wout + (size_t)B * H * L * L;        // B*H*L*L

    float* Qb  = (float*)d_ws;
    float* Kb  = Qb + QKV_ELEMS;
    float* Vb  = Kb + QKV_ELEMS;
    float* wCb = Vb + QKV_ELEMS;
    unsigned char* jCb = (unsigned char*)(wCb + (size_t)NROW * 32);
    __hip_bfloat16* xh = (__hip_bfloat16*)(jCb + (size_t)NROW * 32);
    __hip_bfloat16* xl = xh + (size_t)BL * D;
    __hip_bfloat16* WqTh = xl + (size_t)BL * D;
    __hip_bfloat16* WqTl = WqTh + (size_t)D * D;
    __hip_bfloat16* WkTh = WqTl + (size_t)D * D;
    __hip_bfloat16* WkTl = WkTh + (size_t)D * D;
    __hip_bfloat16* WvT  = WkTl + (size_t)D * D;
    __hip_bfloat16* WoT  = WvT  + (size_t)D * D;
    __hip_bfloat16* consb = xh;   // alias: xh dead after the V / QK GEMMs

    cast_x<<<(BL * D / 4 + 255) / 256, 256, 0, stream>>>(x, xh, xl);
    transpose_w<<<dim3(24, 24, 4), 256, 0, stream>>>(
        Wq, Wk, Wv, Wo, WqTh, WqTl, WkTh, WkTl, WvT, WoT);

    dim3 gmm((BL + 127) / 128, D / 128);
    dim3 gqk((BL + 127) / 128, D / 128, 2);
    gemm_qk_split<<<gqk, 256, 0, stream>>>(
        xh, xl, WqTh, WqTl, WkTh, WkTl, bq, bk, Qb, Kb);
    gemm_bf16<0><<<gmm, 256, 0, stream>>>(xh, WvT, bv, Vb);

    dim3 ga(NBH, 2);
    attn_scores<<<ga, 512, 0, stream>>>(Qb, Kb, lsg, wout, mout, wCb, jCb);
    attn_cons<<<ga, 512, 0, stream>>>(Vb, wCb, jCb, consb);

    gemm_bf16<1><<<gmm, 256, 0, stream>>>(consb, WoT, bo, out);
}

// Round 5
// 357.873 us; speedup vs baseline: 2.5085x; 1.1327x over previous
//
#include <hip/hip_runtime.h>
#include <hip/hip_bf16.h>
#include <math.h>

#define GRIDN 14
#define L 197
#define H 12
#define DK 64
#define D 768
#define B 32
#define BL (B*L)          // 6304
#define TOPK 32
#define NBH (B*H)         // 384
#define NROW (NBH*L)      // 75648
#define QKV_ELEMS ((size_t)NROW*DK)

typedef __attribute__((ext_vector_type(8))) short short8;   // 8 bf16
typedef __attribute__((ext_vector_type(4))) float floatx4;

__device__ __forceinline__ void load_lds16(void* lds, const void* g) {
    __builtin_amdgcn_global_load_lds(
        (const __attribute__((address_space(1))) unsigned int*)g,
        (__attribute__((address_space(3))) unsigned int*)lds, 16, 0, 0);
}

// ---------------------------------------------------------------------------
// prep: z<4 -> LDS-tiled transpose+cast of Wq/Wk/Wv/Wo to bf16 [n][k]
//        (Wq,Wk also emit lo-part); z==4 -> cast x to (hi,lo) bf16.
// grid dim3(24,24,5), 256 threads.
// ---------------------------------------------------------------------------
__global__ __launch_bounds__(256)
void prep(const float* __restrict__ x,
          const float* __restrict__ Wq, const float* __restrict__ Wk,
          const float* __restrict__ Wv, const float* __restrict__ Wo,
          __hip_bfloat16* __restrict__ xh, __hip_bfloat16* __restrict__ xl,
          __hip_bfloat16* __restrict__ WqTh, __hip_bfloat16* __restrict__ WqTl,
          __hip_bfloat16* __restrict__ WkTh, __hip_bfloat16* __restrict__ WkTl,
          __hip_bfloat16* __restrict__ WvT,  __hip_bfloat16* __restrict__ WoT)
{
    const int z = blockIdx.z;
    if (z == 4) {
        int lin = (blockIdx.y * 24 + blockIdx.x) * 256 + threadIdx.x;
        for (int i = lin; i < BL * D / 4; i += 24 * 24 * 256) {
            float4 v = ((const float4*)x)[i];
            union { __hip_bfloat16 b[4]; short4 s; } hh, ll;
            float f[4] = {v.x, v.y, v.z, v.w};
            #pragma unroll
            for (int j = 0; j < 4; ++j) {
                __hip_bfloat16 h = __float2bfloat16(f[j]);
                hh.b[j] = h;
                ll.b[j] = __float2bfloat16(f[j] - __bfloat162float(h));
            }
            ((short4*)xh)[i] = hh.s;
            ((short4*)xl)[i] = ll.s;
        }
        return;
    }
    __shared__ float tile[32][33];
    const float* src = (z == 0) ? Wq : (z == 1) ? Wk : (z == 2) ? Wv : Wo;
    __hip_bfloat16* dh = (z == 0) ? WqTh : (z == 1) ? WkTh : (z == 2) ? WvT : WoT;
    __hip_bfloat16* dl = (z == 0) ? WqTl : (z == 1) ? WkTl : nullptr;
    const int k0 = blockIdx.y * 32, n0 = blockIdx.x * 32;
    const int tx = threadIdx.x & 31, ty = threadIdx.x >> 5;

    for (int r = ty; r < 32; r += 8)
        tile[r][tx] = src[(size_t)(k0 + r) * D + n0 + tx];
    __syncthreads();
    for (int r = ty; r < 32; r += 8) {
        float v = tile[tx][r];
        __hip_bfloat16 h = __float2bfloat16(v);
        dh[(size_t)(n0 + r) * D + k0 + tx] = h;
        if (dl) dl[(size_t)(n0 + r) * D + k0 + tx] =
            __float2bfloat16(v - __bfloat162float(h));
    }
}

// ---------------------------------------------------------------------------
// Fused QKV GEMM: grid (50, 18). blockIdx.y/6 selects Q(3-term) / K(3-term)
// / V(1-term). 128x128 tile, TBK=32, XOR-swizzled LDS (2-way max on reads).
// Writes fp32 (B,H,L,DK).
// ---------------------------------------------------------------------------
__global__ __launch_bounds__(256)
void gemm_qkv(const __hip_bfloat16* __restrict__ xh, const __hip_bfloat16* __restrict__ xl,
              const __hip_bfloat16* __restrict__ Wqh, const __hip_bfloat16* __restrict__ Wql,
              const __hip_bfloat16* __restrict__ Wkh, const __hip_bfloat16* __restrict__ Wkl,
              const __hip_bfloat16* __restrict__ Wvh,
              const float* __restrict__ bq, const float* __restrict__ bk,
              const float* __restrict__ bv,
              float* __restrict__ Qb, float* __restrict__ Kb, float* __restrict__ Vb)
{
    __shared__ __attribute__((aligned(16))) __hip_bfloat16 Ash[128 * 32];
    __shared__ __attribute__((aligned(16))) __hip_bfloat16 Bsh[128 * 32];
    __shared__ __attribute__((aligned(16))) __hip_bfloat16 Asl[128 * 32];
    __shared__ __attribute__((aligned(16))) __hip_bfloat16 Bsl[128 * 32];

    const int grp = blockIdx.y / 6, nt = blockIdx.y % 6;
    const __hip_bfloat16 *Bth, *Btl; const float* bias; float* C;
    if (grp == 0)      { Bth = Wqh; Btl = Wql; bias = bq; C = Qb; }
    else if (grp == 1) { Bth = Wkh; Btl = Wkl; bias = bk; C = Kb; }
    else               { Bth = Wvh; Btl = nullptr; bias = bv; C = Vb; }
    const bool split = (grp < 2);

    const int tid = threadIdx.x;
    const int wave = tid >> 6, lane = tid & 63;
    const int quad = lane >> 4, l16 = lane & 15;
    const int m0 = blockIdx.x * 128, n0 = nt * 128;
    const int wm = (wave & 1) * 64, wn = (wave >> 1) * 64;

    floatx4 acc[4][4] = {};

    int s_r[2], s_cs[2];
    #pragma unroll
    for (int u = 0; u < 2; ++u) {
        int idx = tid + u * 256;
        s_r[u] = idx >> 2; s_cs[u] = idx & 3;
    }

    for (int k0 = 0; k0 < D; k0 += 32) {
        #pragma unroll
        for (int u = 0; u < 2; ++u) {
            int r = s_r[u];
            int csrc = s_cs[u] ^ ((r >> 1) & 3);          // XOR swizzle
            int gm = m0 + r; if (gm >= BL) gm = BL - 1;
            size_t aoff = (size_t)gm * D + k0 + csrc * 8;
            size_t boff = (size_t)(n0 + r) * D + k0 + csrc * 8;
            int lds_off = (wave * 64 + u * 256) * 16;
            load_lds16((char*)Ash + lds_off, xh + aoff);
            load_lds16((char*)Bsh + lds_off, Bth + boff);
            if (split) {
                load_lds16((char*)Asl + lds_off, xl + aoff);
                load_lds16((char*)Bsl + lds_off, Btl + boff);
            }
        }
        __syncthreads();

        short8 ah[4], bh[4];
        #pragma unroll
        for (int a = 0; a < 4; ++a) {
            int r = wm + a * 16 + l16;
            int slot = (r << 2) + (quad ^ ((r >> 1) & 3));
            ah[a] = *(const short8*)((const char*)Ash + (slot << 4));
        }
        #pragma unroll
        for (int b2 = 0; b2 < 4; ++b2) {
            int r = wn + b2 * 16 + l16;
            int slot = (r << 2) + (quad ^ ((r >> 1) & 3));
            bh[b2] = *(const short8*)((const char*)Bsh + (slot << 4));
        }
        if (split) {
            short8 al[4], bl[4];
            #pragma unroll
            for (int a = 0; a < 4; ++a) {
                int r = wm + a * 16 + l16;
                int slot = (r << 2) + (quad ^ ((r >> 1) & 3));
                al[a] = *(const short8*)((const char*)Asl + (slot << 4));
            }
            #pragma unroll
            for (int b2 = 0; b2 < 4; ++b2) {
                int r = wn + b2 * 16 + l16;
                int slot = (r << 2) + (quad ^ ((r >> 1) & 3));
                bl[b2] = *(const short8*)((const char*)Bsl + (slot << 4));
            }
            #pragma unroll
            for (int a = 0; a < 4; ++a)
                #pragma unroll
                for (int b2 = 0; b2 < 4; ++b2) {
                    acc[a][b2] = __builtin_amdgcn_mfma_f32_16x16x32_bf16(
                        al[a], bh[b2], acc[a][b2], 0, 0, 0);
                    acc[a][b2] = __builtin_amdgcn_mfma_f32_16x16x32_bf16(
                        ah[a], bl[b2], acc[a][b2], 0, 0, 0);
                }
        }
        #pragma unroll
        for (int a = 0; a < 4; ++a)
            #pragma unroll
            for (int b2 = 0; b2 < 4; ++b2)
                acc[a][b2] = __builtin_amdgcn_mfma_f32_16x16x32_bf16(
                    ah[a], bh[b2], acc[a][b2], 0, 0, 0);
        __syncthreads();
    }

    #pragma unroll
    for (int b2 = 0; b2 < 4; ++b2) {
        int n = n0 + wn + b2 * 16 + l16;       // 0..767
        float bvv = bias[n];
        int hh = n >> 6, dd = n & 63;
        #pragma unroll
        for (int a = 0; a < 4; ++a) {
            #pragma unroll
            for (int r = 0; r < 4; ++r) {
                int m = m0 + wm + a * 16 + quad * 4 + r;
                if (m < BL) {
                    int bb = m / L, ll = m % L;
                    C[((((size_t)bb * H + hh) * L + ll) << 6) + dd] =
                        acc[a][b2][r] + bvv;
                }
            }
        }
    }
}

// ---------------------------------------------------------------------------
// O-projection GEMM: bf16 single-term, swizzled, row-major fp32 out.
// grid (50, 6).
// ---------------------------------------------------------------------------
__global__ __launch_bounds__(256)
void gemm_o(const __hip_bfloat16* __restrict__ A,
            const __hip_bfloat16* __restrict__ Bt,
            const float* __restrict__ bias, float* __restrict__ C)
{
    __shared__ __attribute__((aligned(16))) __hip_bfloat16 As[128 * 32];
    __shared__ __attribute__((aligned(16))) __hip_bfloat16 Bts[128 * 32];

    const int tid = threadIdx.x;
    const int wave = tid >> 6, lane = tid & 63;
    const int quad = lane >> 4, l16 = lane & 15;
    const int m0 = blockIdx.x * 128, n0 = blockIdx.y * 128;
    const int wm = (wave & 1) * 64, wn = (wave >> 1) * 64;

    floatx4 acc[4][4] = {};

    int s_r[2], s_cs[2];
    #pragma unroll
    for (int u = 0; u < 2; ++u) {
        int idx = tid + u * 256;
        s_r[u] = idx >> 2; s_cs[u] = idx & 3;
    }

    for (int k0 = 0; k0 < D; k0 += 32) {
        #pragma unroll
        for (int u = 0; u < 2; ++u) {
            int r = s_r[u];
            int csrc = s_cs[u] ^ ((r >> 1) & 3);
            int gm = m0 + r; if (gm >= BL) gm = BL - 1;
            int lds_off = (wave * 64 + u * 256) * 16;
            load_lds16((char*)As + lds_off, A + (size_t)gm * D + k0 + csrc * 8);
            load_lds16((char*)Bts + lds_off, Bt + (size_t)(n0 + r) * D + k0 + csrc * 8);
        }
        __syncthreads();

        short8 af[4], bf[4];
        #pragma unroll
        for (int a = 0; a < 4; ++a) {
            int r = wm + a * 16 + l16;
            int slot = (r << 2) + (quad ^ ((r >> 1) & 3));
            af[a] = *(const short8*)((const char*)As + (slot << 4));
        }
        #pragma unroll
        for (int b2 = 0; b2 < 4; ++b2) {
            int r = wn + b2 * 16 + l16;
            int slot = (r << 2) + (quad ^ ((r >> 1) & 3));
            bf[b2] = *(const short8*)((const char*)Bts + (slot << 4));
        }
        #pragma unroll
        for (int a = 0; a < 4; ++a)
            #pragma unroll
            for (int b2 = 0; b2 < 4; ++b2)
                acc[a][b2] = __builtin_amdgcn_mfma_f32_16x16x32_bf16(
                    af[a], bf[b2], acc[a][b2], 0, 0, 0);
        __syncthreads();
    }

    #pragma unroll
    for (int b2 = 0; b2 < 4; ++b2) {
        int n = n0 + wn + b2 * 16 + l16;
        float bvv = bias[n];
        #pragma unroll
        for (int a = 0; a < 4; ++a) {
            #pragma unroll
            for (int r = 0; r < 4; ++r) {
                int m = m0 + wm + a * 16 + quad * 4 + r;
                if (m < BL) C[(size_t)m * D + n] = acc[a][b2][r] + bvv;
            }
        }
    }
}

// ---------------------------------------------------------------------------
// Fused attention: grid (NBH, 2), 512 threads. Phase 1: K in LDS, scores,
// softmax, dense weights/mask, compact (w,j) kept in LDS. Phase 2: V staged
// over the K buffer, consensus from LDS, bf16 output (B,L,D).
// ---------------------------------------------------------------------------
__global__ __launch_bounds__(512)
void attn_fused(const float* __restrict__ Q, const float* __restrict__ Kg,
                const float* __restrict__ Vg, const float* __restrict__ logsig,
                float* __restrict__ wout, float* __restrict__ mout,
                __hip_bfloat16* __restrict__ cons)
{
    __shared__ float KV[L * 65];
    __shared__ float qbuf[8][64];
    __shared__ float ws[8][32];
    __shared__ float clsbuf[L];
    __shared__ float wjW[99][32];
    __shared__ unsigned char wjJ[99][32];

    const int bh = blockIdx.x;
    const int yb = blockIdx.y;
    const int b = bh / H, h = bh % H;
    const int tid = threadIdx.x, wave = tid >> 6, lane = tid & 63;
    const int base_i = yb * 99;

    // ---- phase 1: K staging ----
    const float* Kp = Kg + (size_t)bh * L * DK;
    for (int idx = tid; idx < L * 16; idx += 512) {
        int r = idx >> 4, c4 = idx & 15;
        float4 v = *(const float4*)&Kp[r * 64 + c4 * 4];
        float* dst = &KV[r * 65 + c4 * 4];
        dst[0] = v.x; dst[1] = v.y; dst[2] = v.z; dst[3] = v.w;
    }
    __syncthreads();

    const float coef = -0.5f * expf(-2.0f * logsig[0]);
    const int starts0[9] = {0, 9, 22, 35, 48, 61, 74, 87, 99};
    const int starts1[9] = {99, 112, 124, 136, 148, 161, 173, 185, 197};
    const int i_begin = yb ? starts1[wave] : starts0[wave];
    const int i_end   = yb ? starts1[wave + 1] : starts0[wave + 1];

    for (int i = i_begin; i < i_end; ++i) {
        const int rowid = bh * L + i;
        const size_t wb = (size_t)rowid * L;
        const int local = i - base_i;

        qbuf[wave][lane] = Q[(size_t)rowid * 64 + lane];

        int r0 = 0, c0 = 0, r1 = 0, c1 = 0, Wd = 0, n = L;
        if (i > 0) {
            int r = (i - 1) / GRIDN, c = (i - 1) % GRIDN;
            r0 = r - 2 < 0 ? 0 : r - 2;  r1 = r + 2 > 13 ? 13 : r + 2;
            c0 = c - 2 < 0 ? 0 : c - 2;  c1 = c + 2 > 13 ? 13 : c + 2;
            Wd = c1 - c0 + 1;
            n = (r1 - r0 + 1) * Wd + 1;
        }

        if (i == 0) {
            for (int p = 0; p < 7; ++p) {
                int t = (p << 5) + (lane >> 1);
                bool valid = t < L;
                float s = 0.f;
                if (valid) {
                    const float* kp = &KV[t * 65 + ((lane & 1) << 5)];
                    const float* qp = &qbuf[wave][(lane & 1) << 5];
                    #pragma unroll
                    for (int d2 = 0; d2 < 32; ++d2) {
                        float dv = qp[d2] - kp[d2];
                        s += dv * dv;
                    }
                }
                s += __shfl_xor(s, 1);
                if (valid && !(lane & 1)) clsbuf[t] = coef * s;
            }
            float orig[4], cur[4]; int selb = 0;
            #pragma unroll
            for (int k = 0; k < 4; ++k) {
                int t = lane + (k << 6);
                float v = (t < L) ? clsbuf[t] : -INFINITY;
                orig[k] = v; cur[k] = v;
            }
            float gmax = -INFINITY;
            for (int it = 0; it < TOPK; ++it) {
                float bv = cur[0]; int bt = lane;
                #pragma unroll
                for (int k = 1; k < 4; ++k)
                    if (cur[k] > bv) { bv = cur[k]; bt = lane + (k << 6); }
                #pragma unroll
                for (int off = 32; off; off >>= 1) {
                    float ov = __shfl_xor(bv, off);
                    int   ot = __shfl_xor(bt, off);
                    if (ov > bv || (ov == bv && ot < bt)) { bv = ov; bt = ot; }
                }
                if (it == 0) gmax = bv;
                if ((bt & 63) == lane) { cur[bt >> 6] = -INFINITY; selb |= 1 << (bt >> 6); }
            }
            float zl = 0.f; float wk[4];
            #pragma unroll
            for (int k = 0; k < 4; ++k) {
                wk[k] = ((selb >> k) & 1) ? expf(orig[k] - gmax) : 0.f;
                zl += wk[k];
            }
            #pragma unroll
            for (int off = 32; off; off >>= 1) zl += __shfl_xor(zl, off);

            #pragma unroll
            for (int k = 0; k < 4; ++k) {
                int p = lane + (k << 6);
                if (p < L) {
                    float wv = wk[k] / zl;
                    wout[wb + p] = wv;
                    mout[wb + p] = (wv > 1e-6f) ? 1.f : 0.f;
                }
            }
            int slot = 0;
            #pragma unroll
            for (int k = 0; k < 4; ++k) {
                bool sel = (selb >> k) & 1;
                unsigned long long mk = __ballot(sel);
                if (sel) {
                    int tt = slot + (int)__popcll(mk & ((1ull << lane) - 1ull));
                    wjW[0][tt] = wk[k] / zl;
                    wjJ[0][tt] = (unsigned char)(lane + (k << 6));
                }
                slot += (int)__popcll(mk);
            }
        } else {
            int t = lane >> 1;
            bool valid = t < n;
            float s = 0.f; int j = 0;
            if (valid) {
                if (t > 0) {
                    int tm = t - 1;
                    j = 1 + (r0 + tm / Wd) * GRIDN + (c0 + tm % Wd);
                }
                const float* kp = &KV[j * 65 + ((lane & 1) << 5)];
                const float* qp = &qbuf[wave][(lane & 1) << 5];
                #pragma unroll
                for (int d2 = 0; d2 < 32; ++d2) {
                    float dv = qp[d2] - kp[d2];
                    s += dv * dv;
                }
            }
            s += __shfl_xor(s, 1);
            float sc = valid ? coef * s : -INFINITY;

            float mx = sc;
            #pragma unroll
            for (int off = 32; off; off >>= 1) mx = fmaxf(mx, __shfl_xor(mx, off));
            float e = valid ? expf(sc - mx) : 0.f;
            float es = (lane & 1) ? 0.f : e;
            #pragma unroll
            for (int off = 32; off; off >>= 1) es += __shfl_xor(es, off);
            float wv = e / es;

            if (!(lane & 1)) {
                float wcv = valid ? wv : 0.f;
                ws[wave][t] = wcv;
                wjW[local][t] = wcv;
                wjJ[local][t] = (unsigned char)(valid ? j : 0);
            }
            #pragma unroll
            for (int k = 0; k < 4; ++k) {
                int p = lane + (k << 6);
                if (p < L) {
                    float wd = 0.f;
                    if (p == 0) wd = ws[wave][0];
                    else {
                        int pr = (p - 1) / GRIDN, pc = (p - 1) % GRIDN;
                        if (pr >= r0 && pr <= r1 && pc >= c0 && pc <= c1)
                            wd = ws[wave][1 + (pr - r0) * Wd + (pc - c0)];
                    }
                    wout[wb + p] = wd;
                    mout[wb + p] = (wd > 1e-6f) ? 1.f : 0.f;
                }
            }
        }
    }
    __syncthreads();

    // ---- phase 2: V staging over KV ----
    const float* Vp = Vg + (size_t)bh * L * DK;
    for (int idx = tid; idx < L * 16; idx += 512) {
        int r = idx >> 4, c4 = idx & 15;
        float4 v = *(const float4*)&Vp[r * 64 + c4 * 4];
        float* dst = &KV[r * 65 + c4 * 4];
        dst[0] = v.x; dst[1] = v.y; dst[2] = v.z; dst[3] = v.w;
    }
    __syncthreads();

    const int cstarts0[9] = {0, 13, 26, 38, 50, 62, 74, 87, 99};
    const int c_begin = yb ? starts1[wave] : cstarts0[wave];
    const int c_end   = yb ? starts1[wave + 1] : cstarts0[wave + 1];

    for (int i = c_begin; i < c_end; ++i) {
        const int local = i - base_i;
        float acc = 0.f;
        #pragma unroll
        for (int t = 0; t < 32; ++t) {
            float w = wjW[local][t];          // wave-broadcast LDS read
            int j = wjJ[local][t];
            acc += w * KV[j * 65 + lane];
        }
        cons[((size_t)b * L + i) * D + h * 64 + lane] = __float2bfloat16(acc);
    }
}

// ---------------------------------------------------------------------------
extern "C" void kernel_launch(void* const* d_in, const int* in_sizes, int n_in,
                              void* d_out, int out_size, void* d_ws, size_t ws_size,
                              hipStream_t stream)
{
    const float* x   = (const float*)d_in[0];
    const float* Wq  = (const float*)d_in[1];
    const float* bq  = (const float*)d_in[2];
    const float* Wk  = (const float*)d_in[3];
    const float* bk  = (const float*)d_in[4];
    const float* Wv  = (const float*)d_in[5];
    const float* bv  = (const float*)d_in[6];
    const float* Wo  = (const float*)d_in[7];
    const float* bo  = (const float*)d_in[8];
    const float* lsg = (const float*)d_in[9];

    float* out  = (float*)d_out;                       // B*L*D
    float* wout = out + QKV_ELEMS;                     // B*H*L*L
    float* mout = wout + (size_t)B * H * L * L;        // B*H*L*L

    float* Qb  = (float*)d_ws;
    float* Kb  = Qb + QKV_ELEMS;
    float* Vb  = Kb + QKV_ELEMS;
    __hip_bfloat16* xh = (__hip_bfloat16*)(Vb + QKV_ELEMS);
    __hip_bfloat16* xl = xh + (size_t)BL * D;
    __hip_bfloat16* WqTh = xl + (size_t)BL * D;
    __hip_bfloat16* WqTl = WqTh + (size_t)D * D;
    __hip_bfloat16* WkTh = WqTl + (size_t)D * D;
    __hip_bfloat16* WkTl = WkTh + (size_t)D * D;
    __hip_bfloat16* WvT  = WkTl + (size_t)D * D;
    __hip_bfloat16* WoT  = WvT  + (size_t)D * D;
    __hip_bfloat16* consb = xh;   // alias: xh dead after gemm_qkv

    prep<<<dim3(24, 24, 5), 256, 0, stream>>>(
        x, Wq, Wk, Wv, Wo, xh, xl, WqTh, WqTl, WkTh, WkTl, WvT, WoT);

    gemm_qkv<<<dim3(50, 18), 256, 0, stream>>>(
        xh, xl, WqTh, WqTl, WkTh, WkTl, WvT, bq, bk, bv, Qb, Kb, Vb);

    attn_fused<<<dim3(NBH, 2), 512, 0, stream>>>(
        Qb, Kb, Vb, lsg, wout, mout, consb);

    gemm_o<<<dim3(50, 6), 256, 0, stream>>>(consb, WoT, bo, out);
}

// Round 6
// 344.198 us; speedup vs baseline: 2.6081x; 1.0397x over previous
//
#include <hip/hip_runtime.h>
#include <hip/hip_bf16.h>
#include <math.h>

#define GRIDN 14
#define L 197
#define H 12
#define DK 64
#define D 768
#define B 32
#define BL (B*L)          // 6304
#define TOPK 32
#define NBH (B*H)         // 384
#define NROW (NBH*L)      // 75648
#define QKV_ELEMS ((size_t)NROW*DK)
#define KSTR 68           // KV row stride in floats (float4-aligned, 17 f4)

typedef __attribute__((ext_vector_type(8))) short short8;   // 8 bf16
typedef __attribute__((ext_vector_type(4))) float floatx4;

__device__ __forceinline__ void load_lds16(void* lds, const void* g) {
    __builtin_amdgcn_global_load_lds(
        (const __attribute__((address_space(1))) unsigned int*)g,
        (__attribute__((address_space(3))) unsigned int*)lds, 16, 0, 0);
}

// ---------------------------------------------------------------------------
// prep: z<4 -> LDS-tiled transpose+cast of Wq/Wk/Wv/Wo to bf16 [n][k]
//        (Wq,Wk also emit lo-part); z==4 -> cast x to (hi,lo) bf16.
// ---------------------------------------------------------------------------
__global__ __launch_bounds__(256)
void prep(const float* __restrict__ x,
          const float* __restrict__ Wq, const float* __restrict__ Wk,
          const float* __restrict__ Wv, const float* __restrict__ Wo,
          __hip_bfloat16* __restrict__ xh, __hip_bfloat16* __restrict__ xl,
          __hip_bfloat16* __restrict__ WqTh, __hip_bfloat16* __restrict__ WqTl,
          __hip_bfloat16* __restrict__ WkTh, __hip_bfloat16* __restrict__ WkTl,
          __hip_bfloat16* __restrict__ WvT,  __hip_bfloat16* __restrict__ WoT)
{
    const int z = blockIdx.z;
    if (z == 4) {
        int lin = (blockIdx.y * 24 + blockIdx.x) * 256 + threadIdx.x;
        for (int i = lin; i < BL * D / 4; i += 24 * 24 * 256) {
            float4 v = ((const float4*)x)[i];
            union { __hip_bfloat16 b[4]; short4 s; } hh, ll;
            float f[4] = {v.x, v.y, v.z, v.w};
            #pragma unroll
            for (int j = 0; j < 4; ++j) {
                __hip_bfloat16 h = __float2bfloat16(f[j]);
                hh.b[j] = h;
                ll.b[j] = __float2bfloat16(f[j] - __bfloat162float(h));
            }
            ((short4*)xh)[i] = hh.s;
            ((short4*)xl)[i] = ll.s;
        }
        return;
    }
    __shared__ float tile[32][33];
    const float* src = (z == 0) ? Wq : (z == 1) ? Wk : (z == 2) ? Wv : Wo;
    __hip_bfloat16* dh = (z == 0) ? WqTh : (z == 1) ? WkTh : (z == 2) ? WvT : WoT;
    __hip_bfloat16* dl = (z == 0) ? WqTl : (z == 1) ? WkTl : nullptr;
    const int k0 = blockIdx.y * 32, n0 = blockIdx.x * 32;
    const int tx = threadIdx.x & 31, ty = threadIdx.x >> 5;

    for (int r = ty; r < 32; r += 8)
        tile[r][tx] = src[(size_t)(k0 + r) * D + n0 + tx];
    __syncthreads();
    for (int r = ty; r < 32; r += 8) {
        float v = tile[tx][r];
        __hip_bfloat16 h = __float2bfloat16(v);
        dh[(size_t)(n0 + r) * D + k0 + tx] = h;
        if (dl) dl[(size_t)(n0 + r) * D + k0 + tx] =
            __float2bfloat16(v - __bfloat162float(h));
    }
}

// ---------------------------------------------------------------------------
// Fused QKV GEMM: grid (50, 18). blockIdx.y/6 selects Q(3-term) / K(3-term)
// / V(1-term). 128x128 tile, TBK=32, XOR-swizzled LDS.
// ---------------------------------------------------------------------------
__global__ __launch_bounds__(256)
void gemm_qkv(const __hip_bfloat16* __restrict__ xh, const __hip_bfloat16* __restrict__ xl,
              const __hip_bfloat16* __restrict__ Wqh, const __hip_bfloat16* __restrict__ Wql,
              const __hip_bfloat16* __restrict__ Wkh, const __hip_bfloat16* __restrict__ Wkl,
              const __hip_bfloat16* __restrict__ Wvh,
              const float* __restrict__ bq, const float* __restrict__ bk,
              const float* __restrict__ bv,
              float* __restrict__ Qb, float* __restrict__ Kb, float* __restrict__ Vb)
{
    __shared__ __attribute__((aligned(16))) __hip_bfloat16 Ash[128 * 32];
    __shared__ __attribute__((aligned(16))) __hip_bfloat16 Bsh[128 * 32];
    __shared__ __attribute__((aligned(16))) __hip_bfloat16 Asl[128 * 32];
    __shared__ __attribute__((aligned(16))) __hip_bfloat16 Bsl[128 * 32];

    const int grp = blockIdx.y / 6, nt = blockIdx.y % 6;
    const __hip_bfloat16 *Bth, *Btl; const float* bias; float* C;
    if (grp == 0)      { Bth = Wqh; Btl = Wql; bias = bq; C = Qb; }
    else if (grp == 1) { Bth = Wkh; Btl = Wkl; bias = bk; C = Kb; }
    else               { Bth = Wvh; Btl = nullptr; bias = bv; C = Vb; }
    const bool split = (grp < 2);

    const int tid = threadIdx.x;
    const int wave = tid >> 6, lane = tid & 63;
    const int quad = lane >> 4, l16 = lane & 15;
    const int m0 = blockIdx.x * 128, n0 = nt * 128;
    const int wm = (wave & 1) * 64, wn = (wave >> 1) * 64;

    floatx4 acc[4][4] = {};

    int s_r[2], s_cs[2];
    #pragma unroll
    for (int u = 0; u < 2; ++u) {
        int idx = tid + u * 256;
        s_r[u] = idx >> 2; s_cs[u] = idx & 3;
    }

    for (int k0 = 0; k0 < D; k0 += 32) {
        #pragma unroll
        for (int u = 0; u < 2; ++u) {
            int r = s_r[u];
            int csrc = s_cs[u] ^ ((r >> 1) & 3);          // XOR swizzle
            int gm = m0 + r; if (gm >= BL) gm = BL - 1;
            size_t aoff = (size_t)gm * D + k0 + csrc * 8;
            size_t boff = (size_t)(n0 + r) * D + k0 + csrc * 8;
            int lds_off = (wave * 64 + u * 256) * 16;
            load_lds16((char*)Ash + lds_off, xh + aoff);
            load_lds16((char*)Bsh + lds_off, Bth + boff);
            if (split) {
                load_lds16((char*)Asl + lds_off, xl + aoff);
                load_lds16((char*)Bsl + lds_off, Btl + boff);
            }
        }
        __syncthreads();

        short8 ah[4], bh[4];
        #pragma unroll
        for (int a = 0; a < 4; ++a) {
            int r = wm + a * 16 + l16;
            int slot = (r << 2) + (quad ^ ((r >> 1) & 3));
            ah[a] = *(const short8*)((const char*)Ash + (slot << 4));
        }
        #pragma unroll
        for (int b2 = 0; b2 < 4; ++b2) {
            int r = wn + b2 * 16 + l16;
            int slot = (r << 2) + (quad ^ ((r >> 1) & 3));
            bh[b2] = *(const short8*)((const char*)Bsh + (slot << 4));
        }
        if (split) {
            short8 al[4], bl[4];
            #pragma unroll
            for (int a = 0; a < 4; ++a) {
                int r = wm + a * 16 + l16;
                int slot = (r << 2) + (quad ^ ((r >> 1) & 3));
                al[a] = *(const short8*)((const char*)Asl + (slot << 4));
            }
            #pragma unroll
            for (int b2 = 0; b2 < 4; ++b2) {
                int r = wn + b2 * 16 + l16;
                int slot = (r << 2) + (quad ^ ((r >> 1) & 3));
                bl[b2] = *(const short8*)((const char*)Bsl + (slot << 4));
            }
            #pragma unroll
            for (int a = 0; a < 4; ++a)
                #pragma unroll
                for (int b2 = 0; b2 < 4; ++b2) {
                    acc[a][b2] = __builtin_amdgcn_mfma_f32_16x16x32_bf16(
                        al[a], bh[b2], acc[a][b2], 0, 0, 0);
                    acc[a][b2] = __builtin_amdgcn_mfma_f32_16x16x32_bf16(
                        ah[a], bl[b2], acc[a][b2], 0, 0, 0);
                }
        }
        #pragma unroll
        for (int a = 0; a < 4; ++a)
            #pragma unroll
            for (int b2 = 0; b2 < 4; ++b2)
                acc[a][b2] = __builtin_amdgcn_mfma_f32_16x16x32_bf16(
                    ah[a], bh[b2], acc[a][b2], 0, 0, 0);
        __syncthreads();
    }

    #pragma unroll
    for (int b2 = 0; b2 < 4; ++b2) {
        int n = n0 + wn + b2 * 16 + l16;
        float bvv = bias[n];
        int hh = n >> 6, dd = n & 63;
        #pragma unroll
        for (int a = 0; a < 4; ++a) {
            #pragma unroll
            for (int r = 0; r < 4; ++r) {
                int m = m0 + wm + a * 16 + quad * 4 + r;
                if (m < BL) {
                    int bb = m / L, ll = m % L;
                    C[((((size_t)bb * H + hh) * L + ll) << 6) + dd] =
                        acc[a][b2][r] + bvv;
                }
            }
        }
    }
}

// ---------------------------------------------------------------------------
// O-projection GEMM: bf16 single-term, swizzled, row-major fp32 out.
// ---------------------------------------------------------------------------
__global__ __launch_bounds__(256)
void gemm_o(const __hip_bfloat16* __restrict__ A,
            const __hip_bfloat16* __restrict__ Bt,
            const float* __restrict__ bias, float* __restrict__ C)
{
    __shared__ __attribute__((aligned(16))) __hip_bfloat16 As[128 * 32];
    __shared__ __attribute__((aligned(16))) __hip_bfloat16 Bts[128 * 32];

    const int tid = threadIdx.x;
    const int wave = tid >> 6, lane = tid & 63;
    const int quad = lane >> 4, l16 = lane & 15;
    const int m0 = blockIdx.x * 128, n0 = blockIdx.y * 128;
    const int wm = (wave & 1) * 64, wn = (wave >> 1) * 64;

    floatx4 acc[4][4] = {};

    int s_r[2], s_cs[2];
    #pragma unroll
    for (int u = 0; u < 2; ++u) {
        int idx = tid + u * 256;
        s_r[u] = idx >> 2; s_cs[u] = idx & 3;
    }

    for (int k0 = 0; k0 < D; k0 += 32) {
        #pragma unroll
        for (int u = 0; u < 2; ++u) {
            int r = s_r[u];
            int csrc = s_cs[u] ^ ((r >> 1) & 3);
            int gm = m0 + r; if (gm >= BL) gm = BL - 1;
            int lds_off = (wave * 64 + u * 256) * 16;
            load_lds16((char*)As + lds_off, A + (size_t)gm * D + k0 + csrc * 8);
            load_lds16((char*)Bts + lds_off, Bt + (size_t)(n0 + r) * D + k0 + csrc * 8);
        }
        __syncthreads();

        short8 af[4], bf[4];
        #pragma unroll
        for (int a = 0; a < 4; ++a) {
            int r = wm + a * 16 + l16;
            int slot = (r << 2) + (quad ^ ((r >> 1) & 3));
            af[a] = *(const short8*)((const char*)As + (slot << 4));
        }
        #pragma unroll
        for (int b2 = 0; b2 < 4; ++b2) {
            int r = wn + b2 * 16 + l16;
            int slot = (r << 2) + (quad ^ ((r >> 1) & 3));
            bf[b2] = *(const short8*)((const char*)Bts + (slot << 4));
        }
        #pragma unroll
        for (int a = 0; a < 4; ++a)
            #pragma unroll
            for (int b2 = 0; b2 < 4; ++b2)
                acc[a][b2] = __builtin_amdgcn_mfma_f32_16x16x32_bf16(
                    af[a], bf[b2], acc[a][b2], 0, 0, 0);
        __syncthreads();
    }

    #pragma unroll
    for (int b2 = 0; b2 < 4; ++b2) {
        int n = n0 + wn + b2 * 16 + l16;
        float bvv = bias[n];
        #pragma unroll
        for (int a = 0; a < 4; ++a) {
            #pragma unroll
            for (int r = 0; r < 4; ++r) {
                int m = m0 + wm + a * 16 + quad * 4 + r;
                if (m < BL) C[(size_t)m * D + n] = acc[a][b2][r] + bvv;
            }
        }
    }
}

// ---------------------------------------------------------------------------
// Fused attention: grid (NBH, 2), 512 threads.
// Phase 1: K in LDS (stride 68, f4-aligned), scores via ds_read_b128,
//          Q register-prefetched across the serial row loop.
// Phase 2: V staged over K, consensus from LDS compact lists, bf16 out.
// ---------------------------------------------------------------------------
__global__ __launch_bounds__(512)
void attn_fused(const float* __restrict__ Q, const float* __restrict__ Kg,
                const float* __restrict__ Vg, const float* __restrict__ logsig,
                float* __restrict__ wout, float* __restrict__ mout,
                __hip_bfloat16* __restrict__ cons)
{
    __shared__ __attribute__((aligned(16))) float KV[L * KSTR];
    __shared__ float qbuf[8][64];
    __shared__ float ws[8][32];
    __shared__ float clsbuf[L];
    __shared__ float wjW[99][32];
    __shared__ unsigned char wjJ[99][32];

    const int bh = blockIdx.x;
    const int yb = blockIdx.y;
    const int b = bh / H, h = bh % H;
    const int tid = threadIdx.x, wave = tid >> 6, lane = tid & 63;
    const int base_i = yb * 99;
    const int half = lane & 1;

    // ---- phase 1: K staging (float4, stride 68) ----
    const float* Kp = Kg + (size_t)bh * L * DK;
    for (int idx = tid; idx < L * 16; idx += 512) {
        int r = idx >> 4, c4 = idx & 15;
        *(float4*)&KV[r * KSTR + c4 * 4] = *(const float4*)&Kp[r * 64 + c4 * 4];
    }
    __syncthreads();

    const float coef = -0.5f * expf(-2.0f * logsig[0]);
    const int starts0[9] = {0, 9, 22, 35, 48, 61, 74, 87, 99};
    const int starts1[9] = {99, 112, 124, 136, 148, 161, 173, 185, 197};
    const int i_begin = yb ? starts1[wave] : starts0[wave];
    const int i_end   = yb ? starts1[wave + 1] : starts0[wave + 1];

    // Q register prefetch across the serial row loop
    float qreg = (i_begin < i_end)
               ? Q[((size_t)bh * L + i_begin) * 64 + lane] : 0.f;

    for (int i = i_begin; i < i_end; ++i) {
        const int rowid = bh * L + i;
        const size_t wb = (size_t)rowid * L;
        const int local = i - base_i;

        qbuf[wave][lane] = qreg;                       // in-wave LDS
        if (i + 1 < i_end)
            qreg = Q[((size_t)rowid + 1) * 64 + lane]; // prefetch next row

        int r0 = 0, c0 = 0, r1 = 0, c1 = 0, Wd = 0, n = L;
        if (i > 0) {
            int r = (i - 1) / GRIDN, c = (i - 1) % GRIDN;
            r0 = r - 2 < 0 ? 0 : r - 2;  r1 = r + 2 > 13 ? 13 : r + 2;
            c0 = c - 2 < 0 ? 0 : c - 2;  c1 = c + 2 > 13 ? 13 : c + 2;
            Wd = c1 - c0 + 1;
            n = (r1 - r0 + 1) * Wd + 1;
        }

        if (i == 0) {
            const float4* qp = (const float4*)&qbuf[wave][half << 5];
            for (int p = 0; p < 7; ++p) {
                int t = (p << 5) + (lane >> 1);
                bool valid = t < L;
                float s = 0.f;
                if (valid) {
                    const float4* kp = (const float4*)&KV[t * KSTR + (half << 5)];
                    #pragma unroll
                    for (int d4 = 0; d4 < 8; ++d4) {
                        float4 qv = qp[d4], kv = kp[d4];
                        float dx = qv.x - kv.x, dy = qv.y - kv.y;
                        float dz = qv.z - kv.z, dw = qv.w - kv.w;
                        s += dx * dx + dy * dy + dz * dz + dw * dw;
                    }
                }
                s += __shfl_xor(s, 1);
                if (valid && !half) clsbuf[t] = coef * s;
            }
            float orig[4], cur[4]; int selb = 0;
            #pragma unroll
            for (int k = 0; k < 4; ++k) {
                int t = lane + (k << 6);
                float v = (t < L) ? clsbuf[t] : -INFINITY;
                orig[k] = v; cur[k] = v;
            }
            float gmax = -INFINITY;
            for (int it = 0; it < TOPK; ++it) {
                float bv = cur[0]; int bt = lane;
                #pragma unroll
                for (int k = 1; k < 4; ++k)
                    if (cur[k] > bv) { bv = cur[k]; bt = lane + (k << 6); }
                #pragma unroll
                for (int off = 32; off; off >>= 1) {
                    float ov = __shfl_xor(bv, off);
                    int   ot = __shfl_xor(bt, off);
                    if (ov > bv || (ov == bv && ot < bt)) { bv = ov; bt = ot; }
                }
                if (it == 0) gmax = bv;
                if ((bt & 63) == lane) { cur[bt >> 6] = -INFINITY; selb |= 1 << (bt >> 6); }
            }
            float zl = 0.f; float wk[4];
            #pragma unroll
            for (int k = 0; k < 4; ++k) {
                wk[k] = ((selb >> k) & 1) ? expf(orig[k] - gmax) : 0.f;
                zl += wk[k];
            }
            #pragma unroll
            for (int off = 32; off; off >>= 1) zl += __shfl_xor(zl, off);

            #pragma unroll
            for (int k = 0; k < 4; ++k) {
                int p = lane + (k << 6);
                if (p < L) {
                    float wv = wk[k] / zl;
                    wout[wb + p] = wv;
                    mout[wb + p] = (wv > 1e-6f) ? 1.f : 0.f;
                }
            }
            int slot = 0;
            #pragma unroll
            for (int k = 0; k < 4; ++k) {
                bool sel = (selb >> k) & 1;
                unsigned long long mk = __ballot(sel);
                if (sel) {
                    int tt = slot + (int)__popcll(mk & ((1ull << lane) - 1ull));
                    wjW[0][tt] = wk[k] / zl;
                    wjJ[0][tt] = (unsigned char)(lane + (k << 6));
                }
                slot += (int)__popcll(mk);
            }
        } else {
            int t = lane >> 1;
            bool valid = t < n;
            float s = 0.f; int j = 0;
            if (valid) {
                if (t > 0) {
                    int tm = t - 1;
                    j = 1 + (r0 + tm / Wd) * GRIDN + (c0 + tm % Wd);
                }
                const float4* kp = (const float4*)&KV[j * KSTR + (half << 5)];
                const float4* qp = (const float4*)&qbuf[wave][half << 5];
                #pragma unroll
                for (int d4 = 0; d4 < 8; ++d4) {
                    float4 qv = qp[d4], kv = kp[d4];
                    float dx = qv.x - kv.x, dy = qv.y - kv.y;
                    float dz = qv.z - kv.z, dw = qv.w - kv.w;
                    s += dx * dx + dy * dy + dz * dz + dw * dw;
                }
            }
            s += __shfl_xor(s, 1);
            float sc = valid ? coef * s : -INFINITY;

            float mx = sc;
            #pragma unroll
            for (int off = 32; off; off >>= 1) mx = fmaxf(mx, __shfl_xor(mx, off));
            float e = valid ? expf(sc - mx) : 0.f;
            float es = half ? 0.f : e;
            #pragma unroll
            for (int off = 32; off; off >>= 1) es += __shfl_xor(es, off);
            float wv = e / es;

            if (!half) {
                float wcv = valid ? wv : 0.f;
                ws[wave][t] = wcv;
                wjW[local][t] = wcv;
                wjJ[local][t] = (unsigned char)(valid ? j : 0);
            }
            #pragma unroll
            for (int k = 0; k < 4; ++k) {
                int p = lane + (k << 6);
                if (p < L) {
                    float wd = 0.f;
                    if (p == 0) wd = ws[wave][0];
                    else {
                        int pr = (p - 1) / GRIDN, pc = (p - 1) % GRIDN;
                        if (pr >= r0 && pr <= r1 && pc >= c0 && pc <= c1)
                            wd = ws[wave][1 + (pr - r0) * Wd + (pc - c0)];
                    }
                    wout[wb + p] = wd;
                    mout[wb + p] = (wd > 1e-6f) ? 1.f : 0.f;
                }
            }
        }
    }
    __syncthreads();

    // ---- phase 2: V staging over KV ----
    const float* Vp = Vg + (size_t)bh * L * DK;
    for (int idx = tid; idx < L * 16; idx += 512) {
        int r = idx >> 4, c4 = idx & 15;
        *(float4*)&KV[r * KSTR + c4 * 4] = *(const float4*)&Vp[r * 64 + c4 * 4];
    }
    __syncthreads();

    const int cstarts0[9] = {0, 13, 26, 38, 50, 62, 74, 87, 99};
    const int c_begin = yb ? starts1[wave] : cstarts0[wave];
    const int c_end   = yb ? starts1[wave + 1] : cstarts0[wave + 1];

    for (int i = c_begin; i < c_end; ++i) {
        const int local = i - base_i;
        float acc = 0.f;
        #pragma unroll
        for (int t = 0; t < 32; ++t) {
            float w = wjW[local][t];          // wave-broadcast LDS read
            int j = wjJ[local][t];
            acc += w * KV[j * KSTR + lane];   // 2-way bank alias = free
        }
        cons[((size_t)b * L + i) * D + h * 64 + lane] = __float2bfloat16(acc);
    }
}

// ---------------------------------------------------------------------------
extern "C" void kernel_launch(void* const* d_in, const int* in_sizes, int n_in,
                              void* d_out, int out_size, void* d_ws, size_t ws_size,
                              hipStream_t stream)
{
    const float* x   = (const float*)d_in[0];
    const float* Wq  = (const float*)d_in[1];
    const float* bq  = (const float*)d_in[2];
    const float* Wk  = (const float*)d_in[3];
    const float* bk  = (const float*)d_in[4];
    const float* Wv  = (const float*)d_in[5];
    const float* bv  = (const float*)d_in[6];
    const float* Wo  = (const float*)d_in[7];
    const float* bo  = (const float*)d_in[8];
    const float* lsg = (const float*)d_in[9];

    float* out  = (float*)d_out;                       // B*L*D
    float* wout = out + QKV_ELEMS;                     // B*H*L*L
    float* mout = wout + (size_t)B * H * L * L;        // B*H*L*L

    float* Qb  = (float*)d_ws;
    float* Kb  = Qb + QKV_ELEMS;
    float* Vb  = Kb + QKV_ELEMS;
    __hip_bfloat16* xh = (__hip_bfloat16*)(Vb + QKV_ELEMS);
    __hip_bfloat16* xl = xh + (size_t)BL * D;
    __hip_bfloat16* WqTh = xl + (size_t)BL * D;
    __hip_bfloat16* WqTl = WqTh + (size_t)D * D;
    __hip_bfloat16* WkTh = WqTl + (size_t)D * D;
    __hip_bfloat16* WkTl = WkTh + (size_t)D * D;
    __hip_bfloat16* WvT  = WkTl + (size_t)D * D;
    __hip_bfloat16* WoT  = WvT  + (size_t)D * D;
    __hip_bfloat16* consb = xh;   // alias: xh dead after gemm_qkv

    prep<<<dim3(24, 24, 5), 256, 0, stream>>>(
        x, Wq, Wk, Wv, Wo, xh, xl, WqTh, WqTl, WkTh, WkTl, WvT, WoT);

    gemm_qkv<<<dim3(50, 18), 256, 0, stream>>>(
        xh, xl, WqTh, WqTl, WkTh, WkTl, WvT, bq, bk, bv, Qb, Kb, Vb);

    attn_fused<<<dim3(NBH, 2), 512, 0, stream>>>(
        Qb, Kb, Vb, lsg, wout, mout, consb);

    gemm_o<<<dim3(50, 6), 256, 0, stream>>>(consb, WoT, bo, out);
}

// Round 7
// 333.610 us; speedup vs baseline: 2.6909x; 1.0317x over previous
//
#include <hip/hip_runtime.h>
#include <hip/hip_bf16.h>
#include <math.h>

#define GRIDN 14
#define L 197
#define H 12
#define DK 64
#define D 768
#define B 32
#define BL (B*L)          // 6304
#define TOPK 32
#define NBH (B*H)         // 384
#define NROW (NBH*L)      // 75648
#define QKV_ELEMS ((size_t)NROW*DK)
#define KSTR 68           // KV row stride in floats (float4-aligned, 17 f4)

typedef __attribute__((ext_vector_type(8))) short short8;   // 8 bf16
typedef __attribute__((ext_vector_type(4))) float floatx4;

__device__ __forceinline__ void load_lds16(void* lds, const void* g) {
    __builtin_amdgcn_global_load_lds(
        (const __attribute__((address_space(1))) unsigned int*)g,
        (__attribute__((address_space(3))) unsigned int*)lds, 16, 0, 0);
}

// ---------------------------------------------------------------------------
// prep: z<4 -> LDS-tiled transpose+cast of Wq/Wk/Wv/Wo to bf16 [n][k]
//        (Wq,Wk also emit lo-part); z==4 -> cast x to (hi,lo) bf16.
// ---------------------------------------------------------------------------
__global__ __launch_bounds__(256)
void prep(const float* __restrict__ x,
          const float* __restrict__ Wq, const float* __restrict__ Wk,
          const float* __restrict__ Wv, const float* __restrict__ Wo,
          __hip_bfloat16* __restrict__ xh, __hip_bfloat16* __restrict__ xl,
          __hip_bfloat16* __restrict__ WqTh, __hip_bfloat16* __restrict__ WqTl,
          __hip_bfloat16* __restrict__ WkTh, __hip_bfloat16* __restrict__ WkTl,
          __hip_bfloat16* __restrict__ WvT,  __hip_bfloat16* __restrict__ WoT)
{
    const int z = blockIdx.z;
    if (z == 4) {
        int lin = (blockIdx.y * 24 + blockIdx.x) * 256 + threadIdx.x;
        for (int i = lin; i < BL * D / 4; i += 24 * 24 * 256) {
            float4 v = ((const float4*)x)[i];
            union { __hip_bfloat16 b[4]; short4 s; } hh, ll;
            float f[4] = {v.x, v.y, v.z, v.w};
            #pragma unroll
            for (int j = 0; j < 4; ++j) {
                __hip_bfloat16 h = __float2bfloat16(f[j]);
                hh.b[j] = h;
                ll.b[j] = __float2bfloat16(f[j] - __bfloat162float(h));
            }
            ((short4*)xh)[i] = hh.s;
            ((short4*)xl)[i] = ll.s;
        }
        return;
    }
    __shared__ float tile[32][33];
    const float* src = (z == 0) ? Wq : (z == 1) ? Wk : (z == 2) ? Wv : Wo;
    __hip_bfloat16* dh = (z == 0) ? WqTh : (z == 1) ? WkTh : (z == 2) ? WvT : WoT;
    __hip_bfloat16* dl = (z == 0) ? WqTl : (z == 1) ? WkTl : nullptr;
    const int k0 = blockIdx.y * 32, n0 = blockIdx.x * 32;
    const int tx = threadIdx.x & 31, ty = threadIdx.x >> 5;

    for (int r = ty; r < 32; r += 8)
        tile[r][tx] = src[(size_t)(k0 + r) * D + n0 + tx];
    __syncthreads();
    for (int r = ty; r < 32; r += 8) {
        float v = tile[tx][r];
        __hip_bfloat16 h = __float2bfloat16(v);
        dh[(size_t)(n0 + r) * D + k0 + tx] = h;
        if (dl) dl[(size_t)(n0 + r) * D + k0 + tx] =
            __float2bfloat16(v - __bfloat162float(h));
    }
}

// ---------------------------------------------------------------------------
// Fused QKV GEMM: grid (50, 18). blockIdx.y/6 selects Q(3-term) / K(3-term)
// / V(1-term). 128x128 tile, TBK=32, XOR-swizzled LDS.
// ---------------------------------------------------------------------------
__global__ __launch_bounds__(256)
void gemm_qkv(const __hip_bfloat16* __restrict__ xh, const __hip_bfloat16* __restrict__ xl,
              const __hip_bfloat16* __restrict__ Wqh, const __hip_bfloat16* __restrict__ Wql,
              const __hip_bfloat16* __restrict__ Wkh, const __hip_bfloat16* __restrict__ Wkl,
              const __hip_bfloat16* __restrict__ Wvh,
              const float* __restrict__ bq, const float* __restrict__ bk,
              const float* __restrict__ bv,
              float* __restrict__ Qb, float* __restrict__ Kb, float* __restrict__ Vb)
{
    __shared__ __attribute__((aligned(16))) __hip_bfloat16 Ash[128 * 32];
    __shared__ __attribute__((aligned(16))) __hip_bfloat16 Bsh[128 * 32];
    __shared__ __attribute__((aligned(16))) __hip_bfloat16 Asl[128 * 32];
    __shared__ __attribute__((aligned(16))) __hip_bfloat16 Bsl[128 * 32];

    const int grp = blockIdx.y / 6, nt = blockIdx.y % 6;
    const __hip_bfloat16 *Bth, *Btl; const float* bias; float* C;
    if (grp == 0)      { Bth = Wqh; Btl = Wql; bias = bq; C = Qb; }
    else if (grp == 1) { Bth = Wkh; Btl = Wkl; bias = bk; C = Kb; }
    else               { Bth = Wvh; Btl = nullptr; bias = bv; C = Vb; }
    const bool split = (grp < 2);

    const int tid = threadIdx.x;
    const int wave = tid >> 6, lane = tid & 63;
    const int quad = lane >> 4, l16 = lane & 15;
    const int m0 = blockIdx.x * 128, n0 = nt * 128;
    const int wm = (wave & 1) * 64, wn = (wave >> 1) * 64;

    floatx4 acc[4][4] = {};

    int s_r[2], s_cs[2];
    #pragma unroll
    for (int u = 0; u < 2; ++u) {
        int idx = tid + u * 256;
        s_r[u] = idx >> 2; s_cs[u] = idx & 3;
    }

    for (int k0 = 0; k0 < D; k0 += 32) {
        #pragma unroll
        for (int u = 0; u < 2; ++u) {
            int r = s_r[u];
            int csrc = s_cs[u] ^ ((r >> 1) & 3);          // XOR swizzle
            int gm = m0 + r; if (gm >= BL) gm = BL - 1;
            size_t aoff = (size_t)gm * D + k0 + csrc * 8;
            size_t boff = (size_t)(n0 + r) * D + k0 + csrc * 8;
            int lds_off = (wave * 64 + u * 256) * 16;
            load_lds16((char*)Ash + lds_off, xh + aoff);
            load_lds16((char*)Bsh + lds_off, Bth + boff);
            if (split) {
                load_lds16((char*)Asl + lds_off, xl + aoff);
                load_lds16((char*)Bsl + lds_off, Btl + boff);
            }
        }
        __syncthreads();

        short8 ah[4], bh[4];
        #pragma unroll
        for (int a = 0; a < 4; ++a) {
            int r = wm + a * 16 + l16;
            int slot = (r << 2) + (quad ^ ((r >> 1) & 3));
            ah[a] = *(const short8*)((const char*)Ash + (slot << 4));
        }
        #pragma unroll
        for (int b2 = 0; b2 < 4; ++b2) {
            int r = wn + b2 * 16 + l16;
            int slot = (r << 2) + (quad ^ ((r >> 1) & 3));
            bh[b2] = *(const short8*)((const char*)Bsh + (slot << 4));
        }
        if (split) {
            short8 al[4], bl[4];
            #pragma unroll
            for (int a = 0; a < 4; ++a) {
                int r = wm + a * 16 + l16;
                int slot = (r << 2) + (quad ^ ((r >> 1) & 3));
                al[a] = *(const short8*)((const char*)Asl + (slot << 4));
            }
            #pragma unroll
            for (int b2 = 0; b2 < 4; ++b2) {
                int r = wn + b2 * 16 + l16;
                int slot = (r << 2) + (quad ^ ((r >> 1) & 3));
                bl[b2] = *(const short8*)((const char*)Bsl + (slot << 4));
            }
            #pragma unroll
            for (int a = 0; a < 4; ++a)
                #pragma unroll
                for (int b2 = 0; b2 < 4; ++b2) {
                    acc[a][b2] = __builtin_amdgcn_mfma_f32_16x16x32_bf16(
                        al[a], bh[b2], acc[a][b2], 0, 0, 0);
                    acc[a][b2] = __builtin_amdgcn_mfma_f32_16x16x32_bf16(
                        ah[a], bl[b2], acc[a][b2], 0, 0, 0);
                }
        }
        #pragma unroll
        for (int a = 0; a < 4; ++a)
            #pragma unroll
            for (int b2 = 0; b2 < 4; ++b2)
                acc[a][b2] = __builtin_amdgcn_mfma_f32_16x16x32_bf16(
                    ah[a], bh[b2], acc[a][b2], 0, 0, 0);
        __syncthreads();
    }

    #pragma unroll
    for (int b2 = 0; b2 < 4; ++b2) {
        int n = n0 + wn + b2 * 16 + l16;
        float bvv = bias[n];
        int hh = n >> 6, dd = n & 63;
        #pragma unroll
        for (int a = 0; a < 4; ++a) {
            #pragma unroll
            for (int r = 0; r < 4; ++r) {
                int m = m0 + wm + a * 16 + quad * 4 + r;
                if (m < BL) {
                    int bb = m / L, ll = m % L;
                    C[((((size_t)bb * H + hh) * L + ll) << 6) + dd] =
                        acc[a][b2][r] + bvv;
                }
            }
        }
    }
}

// ---------------------------------------------------------------------------
// O-projection GEMM: bf16 single-term, swizzled, row-major fp32 out.
// ---------------------------------------------------------------------------
__global__ __launch_bounds__(256)
void gemm_o(const __hip_bfloat16* __restrict__ A,
            const __hip_bfloat16* __restrict__ Bt,
            const float* __restrict__ bias, float* __restrict__ C)
{
    __shared__ __attribute__((aligned(16))) __hip_bfloat16 As[128 * 32];
    __shared__ __attribute__((aligned(16))) __hip_bfloat16 Bts[128 * 32];

    const int tid = threadIdx.x;
    const int wave = tid >> 6, lane = tid & 63;
    const int quad = lane >> 4, l16 = lane & 15;
    const int m0 = blockIdx.x * 128, n0 = blockIdx.y * 128;
    const int wm = (wave & 1) * 64, wn = (wave >> 1) * 64;

    floatx4 acc[4][4] = {};

    int s_r[2], s_cs[2];
    #pragma unroll
    for (int u = 0; u < 2; ++u) {
        int idx = tid + u * 256;
        s_r[u] = idx >> 2; s_cs[u] = idx & 3;
    }

    for (int k0 = 0; k0 < D; k0 += 32) {
        #pragma unroll
        for (int u = 0; u < 2; ++u) {
            int r = s_r[u];
            int csrc = s_cs[u] ^ ((r >> 1) & 3);
            int gm = m0 + r; if (gm >= BL) gm = BL - 1;
            int lds_off = (wave * 64 + u * 256) * 16;
            load_lds16((char*)As + lds_off, A + (size_t)gm * D + k0 + csrc * 8);
            load_lds16((char*)Bts + lds_off, Bt + (size_t)(n0 + r) * D + k0 + csrc * 8);
        }
        __syncthreads();

        short8 af[4], bf[4];
        #pragma unroll
        for (int a = 0; a < 4; ++a) {
            int r = wm + a * 16 + l16;
            int slot = (r << 2) + (quad ^ ((r >> 1) & 3));
            af[a] = *(const short8*)((const char*)As + (slot << 4));
        }
        #pragma unroll
        for (int b2 = 0; b2 < 4; ++b2) {
            int r = wn + b2 * 16 + l16;
            int slot = (r << 2) + (quad ^ ((r >> 1) & 3));
            bf[b2] = *(const short8*)((const char*)Bts + (slot << 4));
        }
        #pragma unroll
        for (int a = 0; a < 4; ++a)
            #pragma unroll
            for (int b2 = 0; b2 < 4; ++b2)
                acc[a][b2] = __builtin_amdgcn_mfma_f32_16x16x32_bf16(
                    af[a], bf[b2], acc[a][b2], 0, 0, 0);
        __syncthreads();
    }

    #pragma unroll
    for (int b2 = 0; b2 < 4; ++b2) {
        int n = n0 + wn + b2 * 16 + l16;
        float bvv = bias[n];
        #pragma unroll
        for (int a = 0; a < 4; ++a) {
            #pragma unroll
            for (int r = 0; r < 4; ++r) {
                int m = m0 + wm + a * 16 + quad * 4 + r;
                if (m < BL) C[(size_t)m * D + n] = acc[a][b2][r] + bvv;
            }
        }
    }
}

// ---------------------------------------------------------------------------
// Fused attention: grid (NBH, 2), 512 threads.
// All integer division LUT-ified; per-lane dense positions hoisted.
// Phase 1: K in LDS (stride 68), b128 scores, Q register-prefetched.
// Phase 2: V staged over K, consensus from LDS compact lists, bf16 out.
// ---------------------------------------------------------------------------
__global__ __launch_bounds__(512)
void attn_fused(const float* __restrict__ Q, const float* __restrict__ Kg,
                const float* __restrict__ Vg, const float* __restrict__ logsig,
                float* __restrict__ wout, float* __restrict__ mout,
                __hip_bfloat16* __restrict__ cons)
{
    __shared__ __attribute__((aligned(16))) float KV[L * KSTR];
    __shared__ float qbuf[8][64];
    __shared__ float clsbuf[L];
    __shared__ float wjW[99][32];
    __shared__ unsigned char wjJ[99][32];
    __shared__ unsigned int winA[L];     // r0 | c0<<8 | Wd<<16 | Hh<<24
    __shared__ unsigned int winB[L];     // n | jbase<<8
    __shared__ unsigned char joff[76];   // [Wd-3][tm] -> (tm/Wd)*14 + tm%Wd

    const int bh = blockIdx.x;
    const int yb = blockIdx.y;
    const int b = bh / H, h = bh % H;
    const int tid = threadIdx.x, wave = tid >> 6, lane = tid & 63;
    const int base_i = yb * 99;
    const int half = lane & 1;

    // ---- LUTs (integer division done once per block) ----
    if (tid >= 1 && tid < L) {
        int r = (tid - 1) / GRIDN, c = (tid - 1) % GRIDN;
        int r0 = r - 2 < 0 ? 0 : r - 2, r1 = r + 2 > 13 ? 13 : r + 2;
        int c0 = c - 2 < 0 ? 0 : c - 2, c1 = c + 2 > 13 ? 13 : c + 2;
        int Wd = c1 - c0 + 1, Hh = r1 - r0 + 1;
        winA[tid] = (unsigned)r0 | ((unsigned)c0 << 8) |
                    ((unsigned)Wd << 16) | ((unsigned)Hh << 24);
        winB[tid] = (unsigned)(Hh * Wd + 1) |
                    ((unsigned)(1 + r0 * GRIDN + c0) << 8);
    }
    if (tid == 0) { winA[0] = 0; winB[0] = 0; }
    if (tid < 75) {
        int w = tid / 25 + 3, tm = tid % 25;
        joff[tid] = (unsigned char)((tm / w) * GRIDN + tm % w);
    }

    // per-lane dense-write positions p = lane + 64k, hoisted pr/pc
    int pr4[4], pc4[4];
    #pragma unroll
    for (int k = 0; k < 4; ++k) {
        int p = lane + (k << 6);
        if (p >= 1 && p < L) { pr4[k] = (p - 1) / GRIDN; pc4[k] = (p - 1) % GRIDN; }
        else                 { pr4[k] = 255; pc4[k] = 255; }
    }

    // ---- phase 1: K staging (float4, stride 68) ----
    const float* Kp = Kg + (size_t)bh * L * DK;
    for (int idx = tid; idx < L * 16; idx += 512) {
        int r = idx >> 4, c4 = idx & 15;
        *(float4*)&KV[r * KSTR + c4 * 4] = *(const float4*)&Kp[r * 64 + c4 * 4];
    }
    __syncthreads();

    const float coef = -0.5f * expf(-2.0f * logsig[0]);
    const int starts0[9] = {0, 9, 22, 35, 48, 61, 74, 87, 99};
    const int starts1[9] = {99, 112, 124, 136, 148, 161, 173, 185, 197};
    const int i_begin = yb ? starts1[wave] : starts0[wave];
    const int i_end   = yb ? starts1[wave + 1] : starts0[wave + 1];

    float qreg = (i_begin < i_end)
               ? Q[((size_t)bh * L + i_begin) * 64 + lane] : 0.f;

    for (int i = i_begin; i < i_end; ++i) {
        const int rowid = bh * L + i;
        const size_t wb = (size_t)rowid * L;
        const int local = i - base_i;

        qbuf[wave][lane] = qreg;
        if (i + 1 < i_end)
            qreg = Q[((size_t)rowid + 1) * 64 + lane];

        if (i == 0) {
            const float4* qp = (const float4*)&qbuf[wave][half << 5];
            for (int p = 0; p < 7; ++p) {
                int t = (p << 5) + (lane >> 1);
                bool valid = t < L;
                float s = 0.f;
                if (valid) {
                    const float4* kp = (const float4*)&KV[t * KSTR + (half << 5)];
                    #pragma unroll
                    for (int d4 = 0; d4 < 8; ++d4) {
                        float4 qv = qp[d4], kv = kp[d4];
                        float dx = qv.x - kv.x, dy = qv.y - kv.y;
                        float dz = qv.z - kv.z, dw = qv.w - kv.w;
                        s += dx * dx + dy * dy + dz * dz + dw * dw;
                    }
                }
                s += __shfl_xor(s, 1);
                if (valid && !half) clsbuf[t] = coef * s;
            }
            float orig[4], cur[4]; int selb = 0;
            #pragma unroll
            for (int k = 0; k < 4; ++k) {
                int t = lane + (k << 6);
                float v = (t < L) ? clsbuf[t] : -INFINITY;
                orig[k] = v; cur[k] = v;
            }
            float gmax = -INFINITY;
            for (int it = 0; it < TOPK; ++it) {
                float bv = cur[0]; int bt = lane;
                #pragma unroll
                for (int k = 1; k < 4; ++k)
                    if (cur[k] > bv) { bv = cur[k]; bt = lane + (k << 6); }
                #pragma unroll
                for (int off = 32; off; off >>= 1) {
                    float ov = __shfl_xor(bv, off);
                    int   ot = __shfl_xor(bt, off);
                    if (ov > bv || (ov == bv && ot < bt)) { bv = ov; bt = ot; }
                }
                if (it == 0) gmax = bv;
                if ((bt & 63) == lane) { cur[bt >> 6] = -INFINITY; selb |= 1 << (bt >> 6); }
            }
            float zl = 0.f; float wk[4];
            #pragma unroll
            for (int k = 0; k < 4; ++k) {
                wk[k] = ((selb >> k) & 1) ? expf(orig[k] - gmax) : 0.f;
                zl += wk[k];
            }
            #pragma unroll
            for (int off = 32; off; off >>= 1) zl += __shfl_xor(zl, off);

            #pragma unroll
            for (int k = 0; k < 4; ++k) {
                int p = lane + (k << 6);
                if (p < L) {
                    float wv = wk[k] / zl;
                    wout[wb + p] = wv;
                    mout[wb + p] = (wv > 1e-6f) ? 1.f : 0.f;
                }
            }
            int slot = 0;
            #pragma unroll
            for (int k = 0; k < 4; ++k) {
                bool sel = (selb >> k) & 1;
                unsigned long long mk = __ballot(sel);
                if (sel) {
                    int tt = slot + (int)__popcll(mk & ((1ull << lane) - 1ull));
                    wjW[0][tt] = wk[k] / zl;
                    wjJ[0][tt] = (unsigned char)(lane + (k << 6));
                }
                slot += (int)__popcll(mk);
            }
        } else {
            const unsigned wa = winA[i], wbp = winB[i];
            const int r0 = wa & 255, c0 = (wa >> 8) & 255;
            const int Wd2 = (wa >> 16) & 255, Hh = wa >> 24;
            const int n = wbp & 255, jbase = wbp >> 8;

            int t = lane >> 1;
            bool valid = t < n;
            float s = 0.f; int j = 0;
            if (valid) {
                if (t > 0) j = jbase + joff[(Wd2 - 3) * 25 + (t - 1)];
                const float4* kp = (const float4*)&KV[j * KSTR + (half << 5)];
                const float4* qp = (const float4*)&qbuf[wave][half << 5];
                #pragma unroll
                for (int d4 = 0; d4 < 8; ++d4) {
                    float4 qv = qp[d4], kv = kp[d4];
                    float dx = qv.x - kv.x, dy = qv.y - kv.y;
                    float dz = qv.z - kv.z, dw = qv.w - kv.w;
                    s += dx * dx + dy * dy + dz * dz + dw * dw;
                }
            }
            s += __shfl_xor(s, 1);
            float sc = valid ? coef * s : -INFINITY;

            float mx = sc;
            #pragma unroll
            for (int off = 32; off; off >>= 1) mx = fmaxf(mx, __shfl_xor(mx, off));
            float e = valid ? expf(sc - mx) : 0.f;
            float es = half ? 0.f : e;
            #pragma unroll
            for (int off = 32; off; off >>= 1) es += __shfl_xor(es, off);
            float wv = e / es;

            if (!half) {
                float wcv = valid ? wv : 0.f;
                wjW[local][t] = wcv;
                wjJ[local][t] = (unsigned char)(valid ? j : 0);
            }
            #pragma unroll
            for (int k = 0; k < 4; ++k) {
                int p = lane + (k << 6);
                if (p < L) {
                    float wd = 0.f;
                    if (p == 0) wd = wjW[local][0];
                    else {
                        unsigned du = (unsigned)(pr4[k] - r0);
                        unsigned dv = (unsigned)(pc4[k] - c0);
                        if (du < (unsigned)Hh && dv < (unsigned)Wd2)
                            wd = wjW[local][1 + du * Wd2 + dv];
                    }
                    wout[wb + p] = wd;
                    mout[wb + p] = (wd > 1e-6f) ? 1.f : 0.f;
                }
            }
        }
    }
    __syncthreads();

    // ---- phase 2: V staging over KV ----
    const float* Vp = Vg + (size_t)bh * L * DK;
    for (int idx = tid; idx < L * 16; idx += 512) {
        int r = idx >> 4, c4 = idx & 15;
        *(float4*)&KV[r * KSTR + c4 * 4] = *(const float4*)&Vp[r * 64 + c4 * 4];
    }
    __syncthreads();

    const int cstarts0[9] = {0, 13, 26, 38, 50, 62, 74, 87, 99};
    const int c_begin = yb ? starts1[wave] : cstarts0[wave];
    const int c_end   = yb ? starts1[wave + 1] : cstarts0[wave + 1];

    for (int i = c_begin; i < c_end; ++i) {
        const int local = i - base_i;
        float acc = 0.f;
        #pragma unroll
        for (int t = 0; t < 32; ++t) {
            float w = wjW[local][t];          // wave-broadcast LDS read
            int j = wjJ[local][t];
            acc += w * KV[j * KSTR + lane];   // 2-way bank alias = free
        }
        cons[((size_t)b * L + i) * D + h * 64 + lane] = __float2bfloat16(acc);
    }
}

// ---------------------------------------------------------------------------
extern "C" void kernel_launch(void* const* d_in, const int* in_sizes, int n_in,
                              void* d_out, int out_size, void* d_ws, size_t ws_size,
                              hipStream_t stream)
{
    const float* x   = (const float*)d_in[0];
    const float* Wq  = (const float*)d_in[1];
    const float* bq  = (const float*)d_in[2];
    const float* Wk  = (const float*)d_in[3];
    const float* bk  = (const float*)d_in[4];
    const float* Wv  = (const float*)d_in[5];
    const float* bv  = (const float*)d_in[6];
    const float* Wo  = (const float*)d_in[7];
    const float* bo  = (const float*)d_in[8];
    const float* lsg = (const float*)d_in[9];

    float* out  = (float*)d_out;                       // B*L*D
    float* wout = out + QKV_ELEMS;                     // B*H*L*L
    float* mout = wout + (size_t)B * H * L * L;        // B*H*L*L

    float* Qb  = (float*)d_ws;
    float* Kb  = Qb + QKV_ELEMS;
    float* Vb  = Kb + QKV_ELEMS;
    __hip_bfloat16* xh = (__hip_bfloat16*)(Vb + QKV_ELEMS);
    __hip_bfloat16* xl = xh + (size_t)BL * D;
    __hip_bfloat16* WqTh = xl + (size_t)BL * D;
    __hip_bfloat16* WqTl = WqTh + (size_t)D * D;
    __hip_bfloat16* WkTh = WqTl + (size_t)D * D;
    __hip_bfloat16* WkTl = WkTh + (size_t)D * D;
    __hip_bfloat16* WvT  = WkTl + (size_t)D * D;
    __hip_bfloat16* WoT  = WvT  + (size_t)D * D;
    __hip_bfloat16* consb = xh;   // alias: xh dead after gemm_qkv

    prep<<<dim3(24, 24, 5), 256, 0, stream>>>(
        x, Wq, Wk, Wv, Wo, xh, xl, WqTh, WqTl, WkTh, WkTl, WvT, WoT);

    gemm_qkv<<<dim3(50, 18), 256, 0, stream>>>(
        xh, xl, WqTh, WqTl, WkTh, WkTl, WvT, bq, bk, bv, Qb, Kb, Vb);

    attn_fused<<<dim3(NBH, 2), 512, 0, stream>>>(
        Qb, Kb, Vb, lsg, wout, mout, consb);

    gemm_o<<<dim3(50, 6), 256, 0, stream>>>(consb, WoT, bo, out);
}